// Round 11
// baseline (333.085 us; speedup 1.0000x reference)
//
#include <hip/hip_runtime.h>
#include <float.h>

// ---------------------------------------------------------------------------
// SeqGraphRepNetwork. Round 33 = EXACT RESUBMIT of round 32 (container infra
// failure, kernel never ran). Round 32 = round 31 (279.6us, best) with
// tail_fused de-barriered:
//  - weight B-fragments (Wo/W1/W2) read DIRECTLY from global (L2-resident:
//    32KB each, shared by all ~900 blocks) instead of LDS-staged -> the 3
//    stage loops and their barrier pairs are gone.
//  - Hu staging made wave-local (each wave stages its own 16 rows; LN2 reads
//    only own-wave rows) -> that barrier gone too.
//  - barriers 12 -> 3 (before pooling1 / after pooling1 / before pooling2).
//    LDS tile now holds only block-local activations (out2/relu/ffn2).
// Everything else identical to r31 (head-major k/q + coalesced qkv store,
// attn9 r26 body, halo gather, parallel prep1).
// ---------------------------------------------------------------------------

#define D 128
#define NHEAD 4
#define HD 32
#define MAXL 160
#define MAXNK 10     // max 16-key tiles (L<=160)
#define VP 168       // Vt / Pb key pitch in ushorts
#define WP 136       // LDS tile pitch in ushorts (272B)

typedef __attribute__((ext_vector_type(8))) short short8;
typedef __attribute__((ext_vector_type(4))) float floatx4;

// ---- bf16 <-> f32 helpers --------------------------------------------------
__device__ __forceinline__ float lo2f(unsigned u) {
    union { unsigned i; float f; } x; x.i = u << 16; return x.f;
}
__device__ __forceinline__ float hi2f(unsigned u) {
    union { unsigned i; float f; } x; x.i = u & 0xffff0000u; return x.f;
}
// single-instruction packed f32->bf16 RNE (gfx950 v_cvt_pk_bf16_f32).
// Used in VALU-throughput-bound kernels only (r23 measured: hurts the
// latency-bound attn9 by constraining the scheduler).
__device__ __forceinline__ unsigned pack2(float a, float b) {
    unsigned r;
    asm("v_cvt_pk_bf16_f32 %0, %1, %2" : "=v"(r) : "v"(a), "v"(b));
    return r;
}
__device__ __forceinline__ unsigned short f2bf(float f) {
    return (unsigned short)pack2(f, 0.f);
}
// integer RNE versions (attn9: latency-bound, these schedule freely)
__device__ __forceinline__ unsigned short f2bfi(float f) {
    union { float f; unsigned i; } x; x.f = f;
    unsigned r = x.i + 0x7fffu + ((x.i >> 16) & 1u);
    return (unsigned short)(r >> 16);
}
__device__ __forceinline__ unsigned pack2i(float a, float b) {
    return (unsigned)f2bfi(a) | ((unsigned)f2bfi(b) << 16);
}
__device__ __forceinline__ float bf2f(unsigned short u) {
    union { unsigned i; float f; } x; x.i = (unsigned)u << 16; return x.f;
}

// ---- prep1: c_src/c_dst = a@att_W; u,z refold vectors ----------------------
// 128 blocks x 128 threads: block p, lanes parallel over q.
__launch_bounds__(128)
__global__ void prep1(const float* __restrict__ att_W, const float* __restrict__ a_src,
                      const float* __restrict__ a_dst, const float* __restrict__ in_proj_w,
                      const float* __restrict__ in_proj_b, const float* __restrict__ g1,
                      const float* __restrict__ b1, float* __restrict__ c_src,
                      float* __restrict__ c_dst, float* __restrict__ u, float* __restrict__ z) {
    int p = blockIdx.x;   // output index
    int q = threadIdx.x;  // reduction index
    __shared__ float red[4][2];
    float w  = att_W[q * D + p];      // column p, parallel across lanes
    float wq = in_proj_w[p * D + q];  // row p, coalesced
    float s  = a_src[q] * w;
    float d  = a_dst[q] * w;
    float su = g1[q] * wq;
    float sz = b1[q] * wq;
    #pragma unroll
    for (int o = 32; o; o >>= 1) {
        s  += __shfl_down(s, o, 64);
        d  += __shfl_down(d, o, 64);
        su += __shfl_down(su, o, 64);
        sz += __shfl_down(sz, o, 64);
    }
    int wv = q >> 6;
    if ((q & 63) == 0) { red[0][wv] = s; red[1][wv] = d; red[2][wv] = su; red[3][wv] = sz; }
    __syncthreads();
    if (q == 0) {
        c_src[p] = red[0][0] + red[0][1];
        c_dst[p] = red[1][0] + red[1][1];
        u[p]     = red[2][0] + red[2][1];
        z[p]     = red[3][0] + red[3][1] + in_proj_b[p];
    }
}

// ---- prep2: blocks 0..127 -> tb (4 buckets each); 128..511 -> bf16 weights -
// wb slots: 0 = W'q (Wq*g1), 1 = Wk, 2 = Wv, 3 = Wo, 4 = W1, 5 = W2.
__global__ void prep2(const float* __restrict__ delta, const float* __restrict__ c_src,
                      const float* __restrict__ in_proj_w, const float* __restrict__ out_proj_w,
                      const float* __restrict__ ffn_w1, const float* __restrict__ ffn_w2,
                      const float* __restrict__ ln1_g, float* __restrict__ tb,
                      unsigned short* __restrict__ wb) {
    int blk = blockIdx.x, t = threadIdx.x;
    if (blk < 128) {
        int b = blk * 4 + (t >> 6);
        int l = t & 63;
        const float* row = delta + (size_t)b * D;
        float s = row[l] * c_src[l] + row[l + 64] * c_src[l + 64];
        #pragma unroll
        for (int o = 32; o; o >>= 1) s += __shfl_down(s, o, 64);
        if (l == 0) tb[b] = s;
    } else {
        int idx = (blk - 128) * 256 + t;   // 384*256 = 98304 = 6*128*128
        int m = idx >> 14;
        int within = idx & (D * D - 1);
        float v;
        if (m == 0) v = in_proj_w[within] * ln1_g[within & (D - 1)];
        else if (m == 1) v = in_proj_w[D * D + within];
        else if (m == 2) v = in_proj_w[2 * D * D + within];
        else if (m == 3) v = out_proj_w[within];
        else if (m == 4) v = ffn_w1[within];
        else v = ffn_w2[within];
        wb[idx] = f2bf(v);
    }
}

// ---- gather_hu: block = 8 nodes + 2-row halo; HALF-WAVE per row. -----------
__launch_bounds__(256)
__global__ void gather_hu(const float* __restrict__ POI, const int* __restrict__ sess_idx,
                          const int* __restrict__ node_pos, const int* __restrict__ batch_ids,
                          const int* __restrict__ edge_dist, const int* __restrict__ lengths,
                          const float* __restrict__ c_src, const float* __restrict__ c_dst,
                          const float* __restrict__ tb, unsigned short* __restrict__ Hu,
                          float* __restrict__ muv, float* __restrict__ rinvv,
                          int* __restrict__ starts, int N) {
    __shared__ unsigned xs[10 * 64];      // 2.5 KB packed bf16x2
    __shared__ float s1s[10], s2s[10];
    int R0 = blockIdx.x * 8;
    int t = threadIdx.x;
    int hw = t >> 5, l32 = t & 31;        // 8 half-waves, 32 lanes each
    float4 cs4 = *(const float4*)(c_src + l32 * 4);
    float4 cd4 = *(const float4*)(c_dst + l32 * 4);
    #pragma unroll
    for (int i = hw; i < 10; i += 8) {
        int n = R0 - 1 + i;
        if (n >= 0 && n < N) {
            int row = sess_idx[n];
            float4 v = *(const float4*)(POI + (size_t)row * D + l32 * 4);
            ((uint2*)(xs + i * 64))[l32] = make_uint2(pack2(v.x, v.y), pack2(v.z, v.w));
            if (i >= 1 && i <= 8) {        // halo dots are never used
                float ps = v.x * cs4.x + v.y * cs4.y + v.z * cs4.z + v.w * cs4.w;
                float pd = v.x * cd4.x + v.y * cd4.y + v.z * cd4.z + v.w * cd4.w;
                #pragma unroll
                for (int o = 16; o; o >>= 1) {   // stays within the 32-half
                    ps += __shfl_down(ps, o, 64);
                    pd += __shfl_down(pd, o, 64);
                }
                if (l32 == 0) { s1s[i] = ps; s2s[i] = pd; }
            }
        }
    }
    __syncthreads();
    int j = hw;                            // one node per half-wave
    int n = R0 + j;
    if (n >= N) return;
    int g = batch_ids[n], pos = node_pos[n], L = lengths[g];
    bool hasF = pos > 0;
    bool hasB = pos < L - 1;
    float la = hasF ? (s1s[j + 1] + tb[edge_dist[n - 1 - g]]) : -FLT_MAX;
    float lb = hasB ? s2s[j + 1] : -FLT_MAX;
    float m = fmaxf(la, lb);
    float ea = hasF ? __expf(la - m) : 0.f;
    float eb = hasB ? __expf(lb - m) : 0.f;
    float inv = 1.f / (ea + eb + 1e-16f);
    float wa = ea * inv, wb = eb * inv;
    uint2 a = hasF ? ((const uint2*)(xs + j * 64))[l32] : make_uint2(0u, 0u);
    uint2 b = hasB ? ((const uint2*)(xs + (j + 2) * 64))[l32] : make_uint2(0u, 0u);
    float h0 = wa * lo2f(a.x) + wb * lo2f(b.x);
    float h1 = wa * hi2f(a.x) + wb * hi2f(b.x);
    float h2 = wa * lo2f(a.y) + wb * lo2f(b.y);
    float h3 = wa * hi2f(a.y) + wb * hi2f(b.y);
    ((uint2*)Hu)[(size_t)n * 32 + l32] = make_uint2(pack2(h0, h1), pack2(h2, h3));
    float s = h0 + h1 + h2 + h3;
    float ss = h0 * h0 + h1 * h1 + h2 * h2 + h3 * h3;
    #pragma unroll
    for (int o = 1; o < 32; o <<= 1) {     // xor <=16 stays within the half
        s += __shfl_xor(s, o, 64);
        ss += __shfl_xor(ss, o, 64);
    }
    if (l32 == 0) {
        float mu = s * (1.f / D);
        float var = ss * (1.f / D) - mu * mu;
        muv[n] = mu;
        rinvv[n] = rsqrtf(var + 1e-8f);
        if (pos == 0) starts[g] = n;
    }
}

// ---- qkv_split: grid (gb, 3); blockIdx.y = pass (0=k, 1=v, 2=q refold). ----
// k and q are written HEAD-MAJOR [4][Npad][32]; v transposed [128][Npad].
__launch_bounds__(256)
__global__ void qkv_split(const unsigned short* __restrict__ Hu, const unsigned short* __restrict__ wb,
                          const float* __restrict__ in_proj_b, const float* __restrict__ u,
                          const float* __restrict__ z, const float* __restrict__ muv,
                          const float* __restrict__ rinvv,
                          unsigned short* __restrict__ qo, unsigned short* __restrict__ ko,
                          unsigned short* __restrict__ vT, int M, int Npad) {
    __shared__ unsigned short Wl[128 * WP];
    int t = threadIdx.x;
    int wv = t >> 6, lane = t & 63;
    int quad = lane >> 4, l16 = lane & 15;
    int r0 = blockIdx.x * 128;
    int rbase = r0 + wv * 32;
    int p = blockIdx.y;
    // 1/sqrt(32) * log2(e): attn uses raw v_exp_f32 (2^x) directly
    const float ASCALE = 0.25504364148122793f;
    const unsigned short* W = wb + (p == 0 ? 1 : p == 1 ? 2 : 0) * (D * D);
    for (int i = t; i < 2048; i += 256) {
        int c = i >> 4, kc = (i & 15) * 8;
        *(uint4*)&Wl[c * WP + kc] = *(const uint4*)(W + c * 128 + kc);
    }
    short8 af[2][4];
    #pragma unroll
    for (int mt = 0; mt < 2; mt++) {
        int r = rbase + mt * 16 + l16;
        #pragma unroll
        for (int kk = 0; kk < 4; kk++) {
            if (r < M) af[mt][kk] = *(const short8*)(Hu + (size_t)r * D + kk * 32 + quad * 8);
            else af[mt][kk] = (short8){0, 0, 0, 0, 0, 0, 0, 0};
        }
    }
    __syncthreads();
    floatx4 acc[2][8];
    #pragma unroll
    for (int i = 0; i < 2; i++)
        #pragma unroll
        for (int j = 0; j < 8; j++) acc[i][j] = (floatx4){0.f, 0.f, 0.f, 0.f};
    #pragma unroll
    for (int kk = 0; kk < 4; kk++)
        #pragma unroll
        for (int nt = 0; nt < 8; nt++) {
            short8 bf = *(const short8*)&Wl[(nt * 16 + l16) * WP + kk * 32 + quad * 8];
            acc[0][nt] = __builtin_amdgcn_mfma_f32_16x16x32_bf16(af[0][kk], bf, acc[0][nt], 0, 0, 0);
            acc[1][nt] = __builtin_amdgcn_mfma_f32_16x16x32_bf16(af[1][kk], bf, acc[1][nt], 0, 0, 0);
        }
    __syncthreads();   // all waves done reading Wl weights
    if (p == 1) {          // vT tile: Wl[col][localnode], paired u32 stores
        #pragma unroll
        for (int nt = 0; nt < 8; nt++) {
            int col = nt * 16 + l16;
            float bv = in_proj_b[2 * D + col];
            #pragma unroll
            for (int mt = 0; mt < 2; mt++)
                #pragma unroll
                for (int r = 0; r < 4; r += 2) {
                    int ln = wv * 32 + mt * 16 + quad * 4 + r;
                    float v0 = (r0 + ln     < M) ? acc[mt][nt][r]     + bv : 0.f;
                    float v1 = (r0 + ln + 1 < M) ? acc[mt][nt][r + 1] + bv : 0.f;
                    *(unsigned*)&Wl[col * WP + ln] = pack2(v0, v1);
                }
        }
        __syncthreads();
        for (int i = t; i < 2048; i += 256) {
            int col = i >> 4, c8 = (i & 15) * 8;
            *(uint4*)(vT + (size_t)col * Npad + r0 + c8) = *(uint4*)&Wl[col * WP + c8];
        }
    } else {
        if (p == 0) {      // k tile: Wl[localrow][col]
            #pragma unroll
            for (int nt = 0; nt < 8; nt++) {
                int col = nt * 16 + l16;
                float bv = in_proj_b[D + col];
                #pragma unroll
                for (int mt = 0; mt < 2; mt++)
                    #pragma unroll
                    for (int r = 0; r < 4; r++)
                        Wl[(wv * 32 + mt * 16 + quad * 4 + r) * WP + col] =
                            f2bf(acc[mt][nt][r] + bv);
            }
        } else {           // q refold tile, pre-scaled by 1/sqrt(32)*log2e
            float uc[8], zc[8];
            #pragma unroll
            for (int nt = 0; nt < 8; nt++) {
                uc[nt] = u[nt * 16 + l16];
                zc[nt] = z[nt * 16 + l16] * ASCALE;
            }
            #pragma unroll
            for (int mt = 0; mt < 2; mt++)
                #pragma unroll
                for (int r = 0; r < 4; r++) {
                    int ln = wv * 32 + mt * 16 + quad * 4 + r;
                    int grow = r0 + ln;
                    float mr = grow < M ? muv[grow] : 0.f;
                    float rr = (grow < M ? rinvv[grow] : 0.f) * ASCALE;
                    #pragma unroll
                    for (int nt = 0; nt < 8; nt++)
                        Wl[ln * WP + nt * 16 + l16] =
                            f2bf(rr * (acc[mt][nt][r] - mr * uc[nt]) + zc[nt]);
                }
        }
        __syncthreads();   // store loop reads cross-wave rows
        unsigned short* outp = (p == 0) ? ko : qo;
        // head-slab-major coalesced store: [head][128 rows][32] -- consecutive
        // threads write consecutive 16B inside one head slab (16KB/iteration).
        for (int i = t; i < 2048; i += 256) {
            int head = i >> 9;             // 0..3
            int j = i & 511;
            int row = j >> 2;              // 0..127
            int c = (j & 3) * 8;           // 0,8,16,24
            if (r0 + row < M)
                *(uint4*)(outp + ((size_t)head * Npad + r0 + row) * HD + c) =
                    *(uint4*)&Wl[row * WP + head * 32 + c];
        }
    }
}

// ---- attn9: r26 body + head-major k/q reads (1KB-contiguous wave loads). ---
__launch_bounds__(128)
__global__ void attn9(const unsigned short* __restrict__ qb,
                      const unsigned short* __restrict__ kb,
                      const unsigned short* __restrict__ vT,
                      const int* __restrict__ starts, const int* __restrict__ lengths,
                      unsigned short* __restrict__ ctx, int Npad) {
    __shared__ unsigned short Vt[HD * VP];       // 10.5 KB [dim][key]
    __shared__ unsigned short Pb[2 * 16 * VP];   // 10.5 KB, per-wave halves
    int g = blockIdx.x;
    if (gridDim.x == 1024) {
        int bid = blockIdx.x;
        if (bid < 430) { int r = 96 - bid / 10; g = r + 97 * (bid % 10); }
        else { int b2 = bid - 430; int r = 53 - b2 / 11; g = r + 97 * (b2 % 11); }
    }
    int h = blockIdx.y;
    int start = starts[g], L = lengths[g];
    int t = threadIdx.x;
    int wv = t >> 6, lane = t & 63;
    int l16 = lane & 15, quad = lane >> 4;
    int nk = (L + 15) >> 4;
    int nk2 = (L + 31) >> 5;
    unsigned short* Pw = Pb + wv * 16 * VP;
    // only the odd tail tile is ever read without being written (masked
    // exp stores true zeros for keys in [L, nk*16))
    if (nk & 1) {
        for (int i = lane; i < 128; i += 64) {   // 16 rows x 8 dwords
            int row = i >> 3, c = i & 7;
            ((unsigned*)(Pw + row * VP + nk * 16))[c] = 0u;
        }
    }
    int nch = nk2 * 4;
    for (int i = t; i < HD * nch; i += 128) {
        int r = i / nch, c = i - r * nch;
        *(uint4*)&Vt[r * VP + c * 8] =
            *(const uint4*)(vT + (size_t)(h * HD + r) * Npad + start + c * 8);
    }
    const unsigned short* kh = kb + (size_t)h * Npad * HD;
    const unsigned short* qh = qb + (size_t)h * Npad * HD;
    short8 kf[MAXNK];
    #pragma unroll
    for (int kt = 0; kt < MAXNK; kt++) {
        kf[kt] = (short8){0, 0, 0, 0, 0, 0, 0, 0};
        if (kt < nk) {
            int r = kt * 16 + l16;
            if (r < L) kf[kt] = *(const short8*)(kh + (size_t)(start + r) * HD + quad * 8);
        }
    }
    short8 qf[5];
    #pragma unroll
    for (int i = 0; i < 5; i++) {
        qf[i] = (short8){0, 0, 0, 0, 0, 0, 0, 0};
        int qt = wv + 2 * i;
        if (qt < nk) {
            int qrow = qt * 16 + l16;
            if (qrow < L)
                qf[i] = *(const short8*)(qh + (size_t)(start + qrow) * HD + quad * 8);
        }
    }
    __syncthreads();
    #pragma unroll
    for (int i = 0; i < 5; i++) {
        int qt = wv + 2 * i;
        if (qt >= nk) break;
        int q0 = qt * 16;
        floatx4 sacc[MAXNK];
        #pragma unroll
        for (int kt = 0; kt < MAXNK; kt++)
            if (kt < nk)
                sacc[kt] = __builtin_amdgcn_mfma_f32_16x16x32_bf16(
                    kf[kt], qf[i], (floatx4){0.f, 0.f, 0.f, 0.f}, 0, 0, 0);
        float lsum = 0.f;
        #pragma unroll
        for (int kt = 0; kt < MAXNK; kt++)
            if (kt < nk) {
                #pragma unroll
                for (int r = 0; r < 4; r++) {
                    int key = kt * 16 + quad * 4 + r;
                    // raw 2^x (one v_exp_f32; log2e pre-folded into q)
                    float p = (key < L) ? __builtin_amdgcn_exp2f(sacc[kt][r]) : 0.f;
                    sacc[kt][r] = p;
                    lsum += p;
                }
                *(uint2*)&Pw[l16 * VP + kt * 16 + quad * 4] =
                    make_uint2(pack2i(sacc[kt][0], sacc[kt][1]),
                               pack2i(sacc[kt][2], sacc[kt][3]));
            }
        lsum += __shfl_xor(lsum, 16);
        lsum += __shfl_xor(lsum, 32);
        float inv = 1.f / lsum;
        #pragma unroll
        for (int nc = 0; nc < 2; nc++) {
            // two accumulator chains (kc even/odd): dependent-MFMA chain 5 -> 3
            floatx4 oa = (floatx4){0.f, 0.f, 0.f, 0.f};
            floatx4 ob = (floatx4){0.f, 0.f, 0.f, 0.f};
            #pragma unroll
            for (int kc = 0; kc < 5; kc++)
                if (kc < nk2) {
                    short8 pf = *(const short8*)&Pw[l16 * VP + kc * 32 + quad * 8];
                    short8 vf = *(const short8*)&Vt[(nc * 16 + l16) * VP + kc * 32 + quad * 8];
                    if (kc & 1) ob = __builtin_amdgcn_mfma_f32_16x16x32_bf16(pf, vf, ob, 0, 0, 0);
                    else        oa = __builtin_amdgcn_mfma_f32_16x16x32_bf16(pf, vf, oa, 0, 0, 0);
                }
            #pragma unroll
            for (int r = 0; r < 4; r++) {
                int qr = q0 + quad * 4 + r;
                if (qr < L)
                    ctx[(size_t)(start + qr) * D + h * HD + nc * 16 + l16] =
                        f2bfi((oa[r] + ob[r]) * inv);
            }
        }
    }
}

// ---- tail_fused (512 thr / 8 waves, 3 barriers): weights read from global
// (L2-hot), Hu staged wave-locally. out2 = LN2(ctx@Wo^T + bo + Q);
// ffn = relu(out2@W1^T+b1)@W2^T + b2; S_u += (out2 + ffn) rows / L.
__launch_bounds__(512)
__global__ void tail_fused(const unsigned short* __restrict__ ctx,
                           const unsigned short* __restrict__ Wo,
                           const float* __restrict__ bo,
                           const unsigned short* __restrict__ Hu,
                           const float* __restrict__ muv, const float* __restrict__ rinvv,
                           const float* __restrict__ g1, const float* __restrict__ b1,
                           const float* __restrict__ g2, const float* __restrict__ b2,
                           const unsigned short* __restrict__ W1,
                           const float* __restrict__ b1f,
                           const unsigned short* __restrict__ W2,
                           const float* __restrict__ b2f,
                           const int* __restrict__ batch_ids,
                           const int* __restrict__ lengths,
                           float* __restrict__ out, int M) {
    __shared__ unsigned short Wl[128 * WP];
    __shared__ int gids[128];
    int t = threadIdx.x;
    int wv = t >> 6, lane = t & 63;       // 8 waves, 16 rows each
    int quad = lane >> 4, l16 = lane & 15;
    int r0 = blockIdx.x * 128;
    int rw = wv * 16;                     // wave's local row base
    int rmax = min(128, M - r0);

    if (t < 128) gids[t] = (r0 + t < M) ? batch_ids[r0 + t] : -1;

    // ---- ctx A-fragments + wave-local Hu staging (no barrier needed) -------
    short8 af[4];
    {
        int rA = r0 + rw + l16;
        #pragma unroll
        for (int kk = 0; kk < 4; kk++) {
            if (rA < M) af[kk] = *(const short8*)(ctx + (size_t)rA * D + kk * 32 + quad * 8);
            else af[kk] = (short8){0, 0, 0, 0, 0, 0, 0, 0};
        }
    }
    // each wave stages its OWN 16 rows of Hu (LN2 below reads only these)
    for (int j = lane; j < 256; j += 64) {
        int row = rw + (j >> 4);
        int c8 = (j & 15) * 8;
        uint4 hv = make_uint4(0u, 0u, 0u, 0u);
        if (r0 + row < M) hv = *(const uint4*)(Hu + (size_t)(r0 + row) * D + c8);
        *(uint4*)&Wl[row * WP + c8] = hv;
    }

    // ---- Wo MFMA: B-fragments straight from global (L2-hot) ----------------
    floatx4 acc[8];
    #pragma unroll
    for (int j = 0; j < 8; j++) acc[j] = (floatx4){0.f, 0.f, 0.f, 0.f};
    #pragma unroll
    for (int kk = 0; kk < 4; kk++)
        #pragma unroll
        for (int nt = 0; nt < 8; nt++) {
            short8 bf = *(const short8*)(Wo + (size_t)(nt * 16 + l16) * D + kk * 32 + quad * 8);
            acc[nt] = __builtin_amdgcn_mfma_f32_16x16x32_bf16(af[kk], bf, acc[nt], 0, 0, 0);
        }

    // ---- LN2 epilogue in-place (own-wave rows only) -> Wl = out2 (bf16) ----
    {
        float g1c[8], b1c[8], boc[8], g2c[8], b2c[8];
        #pragma unroll
        for (int nt = 0; nt < 8; nt++) {
            int col = nt * 16 + l16;
            g1c[nt] = g1[col]; b1c[nt] = b1[col]; boc[nt] = bo[col];
            g2c[nt] = g2[col]; b2c[nt] = b2[col];
        }
        #pragma unroll
        for (int r = 0; r < 4; r++) {
            int lrow = rw + quad * 4 + r;
            int grow = r0 + lrow;
            bool ok = grow < M;
            float mr = ok ? muv[grow] : 0.f;
            float rr = ok ? rinvv[grow] : 0.f;
            float vv[8];
            float s = 0.f, ss = 0.f;
            #pragma unroll
            for (int nt = 0; nt < 8; nt++) {
                float huv = bf2f(Wl[lrow * WP + nt * 16 + l16]);
                float qv = (huv - mr) * rr * g1c[nt] + b1c[nt];
                float v = acc[nt][r] + boc[nt] + qv;
                vv[nt] = v;
                s += v; ss += v * v;
            }
            #pragma unroll
            for (int o = 1; o < 16; o <<= 1) {
                s += __shfl_xor(s, o, 64);
                ss += __shfl_xor(ss, o, 64);
            }
            float mu = s * (1.f / D);
            float var = ss * (1.f / D) - mu * mu;
            float rinv = rsqrtf(var + 1e-8f);
            #pragma unroll
            for (int nt = 0; nt < 8; nt++)
                Wl[lrow * WP + nt * 16 + l16] =
                    f2bf((vv[nt] - mu) * rinv * g2c[nt] + b2c[nt]);
        }
    }
    // FFN A-fragments read own-wave rows -- safe before the barrier.
    short8 af2[4];
    #pragma unroll
    for (int kk = 0; kk < 4; kk++)
        af2[kk] = *(const short8*)&Wl[(rw + l16) * WP + kk * 32 + quad * 8];
    __syncthreads();   // barrier 1: pooling reads cross-wave out2

    // ---- pooling pass 1 ----------------------------------------------------
    {
        int d = t & 127, qt = t >> 7;      // 4 quarters x 32 rows
        int rlo = qt * 32, rhi = min(rlo + 32, rmax);
        float sum = 0.f;
        int cur = (rlo < rmax) ? gids[rlo] : -1;
        for (int row = rlo; row < rhi; row++) {
            int g = gids[row];
            if (g != cur) {
                atomicAdd(out + (size_t)cur * D + d, sum / (float)lengths[cur]);
                sum = 0.f; cur = g;
            }
            sum += bf2f(Wl[row * WP + d]);
        }
        if (cur >= 0) atomicAdd(out + (size_t)cur * D + d, sum / (float)lengths[cur]);
    }
    __syncthreads();   // barrier 2: out2 fully consumed before relu overwrite

    // ---- W1 MFMA (global B) -> relu -> own-wave rows of Wl -----------------
    #pragma unroll
    for (int j = 0; j < 8; j++) acc[j] = (floatx4){0.f, 0.f, 0.f, 0.f};
    #pragma unroll
    for (int kk = 0; kk < 4; kk++)
        #pragma unroll
        for (int nt = 0; nt < 8; nt++) {
            short8 bf = *(const short8*)(W1 + (size_t)(nt * 16 + l16) * D + kk * 32 + quad * 8);
            acc[nt] = __builtin_amdgcn_mfma_f32_16x16x32_bf16(af2[kk], bf, acc[nt], 0, 0, 0);
        }
    #pragma unroll
    for (int nt = 0; nt < 8; nt++) {
        int col = nt * 16 + l16;
        float bv = b1f[col];
        #pragma unroll
        for (int r = 0; r < 4; r++)
            Wl[(rw + quad * 4 + r) * WP + col] = f2bf(fmaxf(acc[nt][r] + bv, 0.f));
    }
    // af3 reads own-wave rows written just above -- no barrier needed.
    short8 af3[4];
    #pragma unroll
    for (int kk = 0; kk < 4; kk++)
        af3[kk] = *(const short8*)&Wl[(rw + l16) * WP + kk * 32 + quad * 8];

    // ---- W2 MFMA (global B) -> ffn2 -> own-wave rows of Wl -----------------
    #pragma unroll
    for (int j = 0; j < 8; j++) acc[j] = (floatx4){0.f, 0.f, 0.f, 0.f};
    #pragma unroll
    for (int kk = 0; kk < 4; kk++)
        #pragma unroll
        for (int nt = 0; nt < 8; nt++) {
            short8 bf = *(const short8*)(W2 + (size_t)(nt * 16 + l16) * D + kk * 32 + quad * 8);
            acc[nt] = __builtin_amdgcn_mfma_f32_16x16x32_bf16(af3[kk], bf, acc[nt], 0, 0, 0);
        }
    #pragma unroll
    for (int nt = 0; nt < 8; nt++) {
        int col = nt * 16 + l16;
        float bv = b2f[col];
        #pragma unroll
        for (int r = 0; r < 4; r++)
            Wl[(rw + quad * 4 + r) * WP + col] = f2bf(acc[nt][r] + bv);
    }
    __syncthreads();   // barrier 3: pooling reads cross-wave ffn2

    // ---- pooling pass 2 ----------------------------------------------------
    {
        int d = t & 127, qt = t >> 7;      // 4 quarters x 32 rows
        int rlo = qt * 32, rhi = min(rlo + 32, rmax);
        float sum = 0.f;
        int cur = (rlo < rmax) ? gids[rlo] : -1;
        for (int row = rlo; row < rhi; row++) {
            int g = gids[row];
            if (g != cur) {
                atomicAdd(out + (size_t)cur * D + d, sum / (float)lengths[cur]);
                sum = 0.f; cur = g;
            }
            sum += bf2f(Wl[row * WP + d]);
        }
        if (cur >= 0) atomicAdd(out + (size_t)cur * D + d, sum / (float)lengths[cur]);
    }
}

// ---------------------------------------------------------------------------
extern "C" void kernel_launch(void* const* d_in, const int* in_sizes, int n_in,
                              void* d_out, int out_size, void* d_ws, size_t ws_size,
                              hipStream_t stream) {
    const float* POI        = (const float*)d_in[0];
    const float* delta      = (const float*)d_in[1];
    const float* att_W      = (const float*)d_in[2];
    const float* a_src      = (const float*)d_in[3];
    const float* a_dst      = (const float*)d_in[4];
    const float* in_proj_w  = (const float*)d_in[5];
    const float* in_proj_b  = (const float*)d_in[6];
    const float* out_proj_w = (const float*)d_in[7];
    const float* out_proj_b = (const float*)d_in[8];
    const float* ln1_g      = (const float*)d_in[9];
    const float* ln1_b      = (const float*)d_in[10];
    const float* ln2_g      = (const float*)d_in[11];
    const float* ln2_b      = (const float*)d_in[12];
    const float* ffn_w1     = (const float*)d_in[13];
    const float* ffn_b1     = (const float*)d_in[14];
    const float* ffn_w2     = (const float*)d_in[15];
    const float* ffn_b2     = (const float*)d_in[16];
    const int* sess_idx     = (const int*)d_in[17];
    const int* edge_dist    = (const int*)d_in[18];
    const int* batch_ids    = (const int*)d_in[20];
    const int* node_pos     = (const int*)d_in[21];
    const int* lengths      = (const int*)d_in[22];

    int N = in_sizes[17];
    int B = in_sizes[22];
    int gb = (N + 127) / 128;
    int Npad = gb * 128;

    // ---- workspace layout in BYTES, 256-aligned blocks ---------------------
    char* base = (char*)d_ws;
    size_t off = 0;
    auto alloc = [&](size_t bytes) { size_t c = off; off = (off + bytes + 255) & ~(size_t)255; return c; };
    size_t o_csrc  = alloc(D * 4);
    size_t o_cdst  = alloc(D * 4);
    size_t o_t     = alloc(512 * 4);
    size_t o_start = alloc((size_t)B * 4);
    size_t o_mu    = alloc((size_t)N * 4);
    size_t o_ri    = alloc((size_t)N * 4);
    size_t o_u     = alloc(D * 4);
    size_t o_z     = alloc(D * 4);
    size_t o_wb    = alloc(6 * D * D * 2);
    size_t nb      = (size_t)Npad * D * 2;       // one bf16 [Npad,128] buffer
    size_t o_A = alloc(nb);
    size_t o_B = alloc(nb);
    size_t o_C = alloc(nb);
    size_t o_D = alloc(nb);
    if (ws_size < off) return;   // diagnostic: silent fail, no GPU fault

    float* c_src = (float*)(base + o_csrc);
    float* c_dst = (float*)(base + o_cdst);
    float* tb    = (float*)(base + o_t);
    int*   starts = (int*)(base + o_start);
    float* muv   = (float*)(base + o_mu);
    float* rinvv = (float*)(base + o_ri);
    float* u     = (float*)(base + o_u);
    float* z     = (float*)(base + o_z);
    unsigned short* wb = (unsigned short*)(base + o_wb);
    unsigned short* bufA = (unsigned short*)(base + o_A);
    unsigned short* bufB = (unsigned short*)(base + o_B);
    unsigned short* bufC = (unsigned short*)(base + o_C);
    unsigned short* bufD = (unsigned short*)(base + o_D);

    // ---- pipeline ----------------------------------------------------------
    hipMemsetAsync(d_out, 0, (size_t)B * D * 4, stream);   // pooled via atomics
    prep1<<<128, 128, 0, stream>>>(att_W, a_src, a_dst, in_proj_w, in_proj_b,
                                   ln1_g, ln1_b, c_src, c_dst, u, z);
    prep2<<<512, 256, 0, stream>>>(delta, c_src, in_proj_w, out_proj_w,
                                   ffn_w1, ffn_w2, ln1_g, tb, wb);
    gather_hu<<<(N + 7) / 8, 256, 0, stream>>>(POI, sess_idx, node_pos, batch_ids,
                                               edge_dist, lengths, c_src, c_dst, tb,
                                               bufB, muv, rinvv, starts, N);    // Hu=B

    qkv_split<<<dim3(gb, 3), 256, 0, stream>>>(bufB, wb, in_proj_b, u, z, muv, rinvv,
                                               bufC, bufD, bufA, N, Npad);   // q=C, k=D, vT=A

    attn9<<<dim3(B, NHEAD), 128, 0, stream>>>(bufC, bufD, bufA, starts, lengths, bufC, Npad); // ctx=C

    tail_fused<<<gb, 512, 0, stream>>>(bufC, wb + 3 * D * D, out_proj_b, bufB, muv, rinvv,
                                       ln1_g, ln1_b, ln2_g, ln2_b,
                                       wb + 4 * D * D, ffn_b1, wb + 5 * D * D, ffn_b2,
                                       batch_ids, lengths, (float*)d_out, N);
}

// Round 12
// 279.277 us; speedup vs baseline: 1.1927x; 1.1927x over previous
//
#include <hip/hip_runtime.h>
#include <float.h>

// ---------------------------------------------------------------------------
// SeqGraphRepNetwork. Round 34 = EXACT REVERT to round 31 (279.6us, verified
// best). Round 32/33's global-direct weight B-fragments REFUTED: FETCH flat
// (weights were L2-hot) and conflicts -92%, but tail_fused 55->118us -- the
// removed barriers (~13us) were replaced by ~63us of exposed L2 latency on
// the MFMA B-path. LDS-staged weights + ds_read IS the latency-amortization
// mechanism; keep it.
// Configuration: head-major k/q [4][Npad][32] + coalesced head-slab qkv
// store, attn9 r26 body (Vt+Pb LDS, PV 2-chain), tail_fused 512thr/8wave
// LDS-staged weights, halo gather, parallel prep1.
// ---------------------------------------------------------------------------

#define D 128
#define NHEAD 4
#define HD 32
#define MAXL 160
#define MAXNK 10     // max 16-key tiles (L<=160)
#define VP 168       // Vt / Pb key pitch in ushorts
#define WP 136       // LDS tile pitch in ushorts (272B)

typedef __attribute__((ext_vector_type(8))) short short8;
typedef __attribute__((ext_vector_type(4))) float floatx4;

// ---- bf16 <-> f32 helpers --------------------------------------------------
__device__ __forceinline__ float lo2f(unsigned u) {
    union { unsigned i; float f; } x; x.i = u << 16; return x.f;
}
__device__ __forceinline__ float hi2f(unsigned u) {
    union { unsigned i; float f; } x; x.i = u & 0xffff0000u; return x.f;
}
// single-instruction packed f32->bf16 RNE (gfx950 v_cvt_pk_bf16_f32).
// Used in VALU-throughput-bound kernels only (r23 measured: hurts the
// latency-bound attn9 by constraining the scheduler).
__device__ __forceinline__ unsigned pack2(float a, float b) {
    unsigned r;
    asm("v_cvt_pk_bf16_f32 %0, %1, %2" : "=v"(r) : "v"(a), "v"(b));
    return r;
}
__device__ __forceinline__ unsigned short f2bf(float f) {
    return (unsigned short)pack2(f, 0.f);
}
// integer RNE versions (attn9: latency-bound, these schedule freely)
__device__ __forceinline__ unsigned short f2bfi(float f) {
    union { float f; unsigned i; } x; x.f = f;
    unsigned r = x.i + 0x7fffu + ((x.i >> 16) & 1u);
    return (unsigned short)(r >> 16);
}
__device__ __forceinline__ unsigned pack2i(float a, float b) {
    return (unsigned)f2bfi(a) | ((unsigned)f2bfi(b) << 16);
}
__device__ __forceinline__ float bf2f(unsigned short u) {
    union { unsigned i; float f; } x; x.i = (unsigned)u << 16; return x.f;
}

// ---- prep1: c_src/c_dst = a@att_W; u,z refold vectors ----------------------
// 128 blocks x 128 threads: block p, lanes parallel over q.
__launch_bounds__(128)
__global__ void prep1(const float* __restrict__ att_W, const float* __restrict__ a_src,
                      const float* __restrict__ a_dst, const float* __restrict__ in_proj_w,
                      const float* __restrict__ in_proj_b, const float* __restrict__ g1,
                      const float* __restrict__ b1, float* __restrict__ c_src,
                      float* __restrict__ c_dst, float* __restrict__ u, float* __restrict__ z) {
    int p = blockIdx.x;   // output index
    int q = threadIdx.x;  // reduction index
    __shared__ float red[4][2];
    float w  = att_W[q * D + p];      // column p, parallel across lanes
    float wq = in_proj_w[p * D + q];  // row p, coalesced
    float s  = a_src[q] * w;
    float d  = a_dst[q] * w;
    float su = g1[q] * wq;
    float sz = b1[q] * wq;
    #pragma unroll
    for (int o = 32; o; o >>= 1) {
        s  += __shfl_down(s, o, 64);
        d  += __shfl_down(d, o, 64);
        su += __shfl_down(su, o, 64);
        sz += __shfl_down(sz, o, 64);
    }
    int wv = q >> 6;
    if ((q & 63) == 0) { red[0][wv] = s; red[1][wv] = d; red[2][wv] = su; red[3][wv] = sz; }
    __syncthreads();
    if (q == 0) {
        c_src[p] = red[0][0] + red[0][1];
        c_dst[p] = red[1][0] + red[1][1];
        u[p]     = red[2][0] + red[2][1];
        z[p]     = red[3][0] + red[3][1] + in_proj_b[p];
    }
}

// ---- prep2: blocks 0..127 -> tb (4 buckets each); 128..511 -> bf16 weights -
// wb slots: 0 = W'q (Wq*g1), 1 = Wk, 2 = Wv, 3 = Wo, 4 = W1, 5 = W2.
__global__ void prep2(const float* __restrict__ delta, const float* __restrict__ c_src,
                      const float* __restrict__ in_proj_w, const float* __restrict__ out_proj_w,
                      const float* __restrict__ ffn_w1, const float* __restrict__ ffn_w2,
                      const float* __restrict__ ln1_g, float* __restrict__ tb,
                      unsigned short* __restrict__ wb) {
    int blk = blockIdx.x, t = threadIdx.x;
    if (blk < 128) {
        int b = blk * 4 + (t >> 6);
        int l = t & 63;
        const float* row = delta + (size_t)b * D;
        float s = row[l] * c_src[l] + row[l + 64] * c_src[l + 64];
        #pragma unroll
        for (int o = 32; o; o >>= 1) s += __shfl_down(s, o, 64);
        if (l == 0) tb[b] = s;
    } else {
        int idx = (blk - 128) * 256 + t;   // 384*256 = 98304 = 6*128*128
        int m = idx >> 14;
        int within = idx & (D * D - 1);
        float v;
        if (m == 0) v = in_proj_w[within] * ln1_g[within & (D - 1)];
        else if (m == 1) v = in_proj_w[D * D + within];
        else if (m == 2) v = in_proj_w[2 * D * D + within];
        else if (m == 3) v = out_proj_w[within];
        else if (m == 4) v = ffn_w1[within];
        else v = ffn_w2[within];
        wb[idx] = f2bf(v);
    }
}

// ---- gather_hu: block = 8 nodes + 2-row halo; HALF-WAVE per row. -----------
__launch_bounds__(256)
__global__ void gather_hu(const float* __restrict__ POI, const int* __restrict__ sess_idx,
                          const int* __restrict__ node_pos, const int* __restrict__ batch_ids,
                          const int* __restrict__ edge_dist, const int* __restrict__ lengths,
                          const float* __restrict__ c_src, const float* __restrict__ c_dst,
                          const float* __restrict__ tb, unsigned short* __restrict__ Hu,
                          float* __restrict__ muv, float* __restrict__ rinvv,
                          int* __restrict__ starts, int N) {
    __shared__ unsigned xs[10 * 64];      // 2.5 KB packed bf16x2
    __shared__ float s1s[10], s2s[10];
    int R0 = blockIdx.x * 8;
    int t = threadIdx.x;
    int hw = t >> 5, l32 = t & 31;        // 8 half-waves, 32 lanes each
    float4 cs4 = *(const float4*)(c_src + l32 * 4);
    float4 cd4 = *(const float4*)(c_dst + l32 * 4);
    #pragma unroll
    for (int i = hw; i < 10; i += 8) {
        int n = R0 - 1 + i;
        if (n >= 0 && n < N) {
            int row = sess_idx[n];
            float4 v = *(const float4*)(POI + (size_t)row * D + l32 * 4);
            ((uint2*)(xs + i * 64))[l32] = make_uint2(pack2(v.x, v.y), pack2(v.z, v.w));
            if (i >= 1 && i <= 8) {        // halo dots are never used
                float ps = v.x * cs4.x + v.y * cs4.y + v.z * cs4.z + v.w * cs4.w;
                float pd = v.x * cd4.x + v.y * cd4.y + v.z * cd4.z + v.w * cd4.w;
                #pragma unroll
                for (int o = 16; o; o >>= 1) {   // stays within the 32-half
                    ps += __shfl_down(ps, o, 64);
                    pd += __shfl_down(pd, o, 64);
                }
                if (l32 == 0) { s1s[i] = ps; s2s[i] = pd; }
            }
        }
    }
    __syncthreads();
    int j = hw;                            // one node per half-wave
    int n = R0 + j;
    if (n >= N) return;
    int g = batch_ids[n], pos = node_pos[n], L = lengths[g];
    bool hasF = pos > 0;
    bool hasB = pos < L - 1;
    float la = hasF ? (s1s[j + 1] + tb[edge_dist[n - 1 - g]]) : -FLT_MAX;
    float lb = hasB ? s2s[j + 1] : -FLT_MAX;
    float m = fmaxf(la, lb);
    float ea = hasF ? __expf(la - m) : 0.f;
    float eb = hasB ? __expf(lb - m) : 0.f;
    float inv = 1.f / (ea + eb + 1e-16f);
    float wa = ea * inv, wb = eb * inv;
    uint2 a = hasF ? ((const uint2*)(xs + j * 64))[l32] : make_uint2(0u, 0u);
    uint2 b = hasB ? ((const uint2*)(xs + (j + 2) * 64))[l32] : make_uint2(0u, 0u);
    float h0 = wa * lo2f(a.x) + wb * lo2f(b.x);
    float h1 = wa * hi2f(a.x) + wb * hi2f(b.x);
    float h2 = wa * lo2f(a.y) + wb * lo2f(b.y);
    float h3 = wa * hi2f(a.y) + wb * hi2f(b.y);
    ((uint2*)Hu)[(size_t)n * 32 + l32] = make_uint2(pack2(h0, h1), pack2(h2, h3));
    float s = h0 + h1 + h2 + h3;
    float ss = h0 * h0 + h1 * h1 + h2 * h2 + h3 * h3;
    #pragma unroll
    for (int o = 1; o < 32; o <<= 1) {     // xor <=16 stays within the half
        s += __shfl_xor(s, o, 64);
        ss += __shfl_xor(ss, o, 64);
    }
    if (l32 == 0) {
        float mu = s * (1.f / D);
        float var = ss * (1.f / D) - mu * mu;
        muv[n] = mu;
        rinvv[n] = rsqrtf(var + 1e-8f);
        if (pos == 0) starts[g] = n;
    }
}

// ---- qkv_split: grid (gb, 3); blockIdx.y = pass (0=k, 1=v, 2=q refold). ----
// k and q are written HEAD-MAJOR [4][Npad][32]; v transposed [128][Npad].
__launch_bounds__(256)
__global__ void qkv_split(const unsigned short* __restrict__ Hu, const unsigned short* __restrict__ wb,
                          const float* __restrict__ in_proj_b, const float* __restrict__ u,
                          const float* __restrict__ z, const float* __restrict__ muv,
                          const float* __restrict__ rinvv,
                          unsigned short* __restrict__ qo, unsigned short* __restrict__ ko,
                          unsigned short* __restrict__ vT, int M, int Npad) {
    __shared__ unsigned short Wl[128 * WP];
    int t = threadIdx.x;
    int wv = t >> 6, lane = t & 63;
    int quad = lane >> 4, l16 = lane & 15;
    int r0 = blockIdx.x * 128;
    int rbase = r0 + wv * 32;
    int p = blockIdx.y;
    // 1/sqrt(32) * log2(e): attn uses raw v_exp_f32 (2^x) directly
    const float ASCALE = 0.25504364148122793f;
    const unsigned short* W = wb + (p == 0 ? 1 : p == 1 ? 2 : 0) * (D * D);
    for (int i = t; i < 2048; i += 256) {
        int c = i >> 4, kc = (i & 15) * 8;
        *(uint4*)&Wl[c * WP + kc] = *(const uint4*)(W + c * 128 + kc);
    }
    short8 af[2][4];
    #pragma unroll
    for (int mt = 0; mt < 2; mt++) {
        int r = rbase + mt * 16 + l16;
        #pragma unroll
        for (int kk = 0; kk < 4; kk++) {
            if (r < M) af[mt][kk] = *(const short8*)(Hu + (size_t)r * D + kk * 32 + quad * 8);
            else af[mt][kk] = (short8){0, 0, 0, 0, 0, 0, 0, 0};
        }
    }
    __syncthreads();
    floatx4 acc[2][8];
    #pragma unroll
    for (int i = 0; i < 2; i++)
        #pragma unroll
        for (int j = 0; j < 8; j++) acc[i][j] = (floatx4){0.f, 0.f, 0.f, 0.f};
    #pragma unroll
    for (int kk = 0; kk < 4; kk++)
        #pragma unroll
        for (int nt = 0; nt < 8; nt++) {
            short8 bf = *(const short8*)&Wl[(nt * 16 + l16) * WP + kk * 32 + quad * 8];
            acc[0][nt] = __builtin_amdgcn_mfma_f32_16x16x32_bf16(af[0][kk], bf, acc[0][nt], 0, 0, 0);
            acc[1][nt] = __builtin_amdgcn_mfma_f32_16x16x32_bf16(af[1][kk], bf, acc[1][nt], 0, 0, 0);
        }
    __syncthreads();   // all waves done reading Wl weights
    if (p == 1) {          // vT tile: Wl[col][localnode], paired u32 stores
        #pragma unroll
        for (int nt = 0; nt < 8; nt++) {
            int col = nt * 16 + l16;
            float bv = in_proj_b[2 * D + col];
            #pragma unroll
            for (int mt = 0; mt < 2; mt++)
                #pragma unroll
                for (int r = 0; r < 4; r += 2) {
                    int ln = wv * 32 + mt * 16 + quad * 4 + r;
                    float v0 = (r0 + ln     < M) ? acc[mt][nt][r]     + bv : 0.f;
                    float v1 = (r0 + ln + 1 < M) ? acc[mt][nt][r + 1] + bv : 0.f;
                    *(unsigned*)&Wl[col * WP + ln] = pack2(v0, v1);
                }
        }
        __syncthreads();
        for (int i = t; i < 2048; i += 256) {
            int col = i >> 4, c8 = (i & 15) * 8;
            *(uint4*)(vT + (size_t)col * Npad + r0 + c8) = *(uint4*)&Wl[col * WP + c8];
        }
    } else {
        if (p == 0) {      // k tile: Wl[localrow][col]
            #pragma unroll
            for (int nt = 0; nt < 8; nt++) {
                int col = nt * 16 + l16;
                float bv = in_proj_b[D + col];
                #pragma unroll
                for (int mt = 0; mt < 2; mt++)
                    #pragma unroll
                    for (int r = 0; r < 4; r++)
                        Wl[(wv * 32 + mt * 16 + quad * 4 + r) * WP + col] =
                            f2bf(acc[mt][nt][r] + bv);
            }
        } else {           // q refold tile, pre-scaled by 1/sqrt(32)*log2e
            float uc[8], zc[8];
            #pragma unroll
            for (int nt = 0; nt < 8; nt++) {
                uc[nt] = u[nt * 16 + l16];
                zc[nt] = z[nt * 16 + l16] * ASCALE;
            }
            #pragma unroll
            for (int mt = 0; mt < 2; mt++)
                #pragma unroll
                for (int r = 0; r < 4; r++) {
                    int ln = wv * 32 + mt * 16 + quad * 4 + r;
                    int grow = r0 + ln;
                    float mr = grow < M ? muv[grow] : 0.f;
                    float rr = (grow < M ? rinvv[grow] : 0.f) * ASCALE;
                    #pragma unroll
                    for (int nt = 0; nt < 8; nt++)
                        Wl[ln * WP + nt * 16 + l16] =
                            f2bf(rr * (acc[mt][nt][r] - mr * uc[nt]) + zc[nt]);
                }
        }
        __syncthreads();   // store loop reads cross-wave rows
        unsigned short* outp = (p == 0) ? ko : qo;
        // head-slab-major coalesced store: [head][128 rows][32] -- consecutive
        // threads write consecutive 16B inside one head slab (16KB/iteration).
        for (int i = t; i < 2048; i += 256) {
            int head = i >> 9;             // 0..3
            int j = i & 511;
            int row = j >> 2;              // 0..127
            int c = (j & 3) * 8;           // 0,8,16,24
            if (r0 + row < M)
                *(uint4*)(outp + ((size_t)head * Npad + r0 + row) * HD + c) =
                    *(uint4*)&Wl[row * WP + head * 32 + c];
        }
    }
}

// ---- attn9: r26 body + head-major k/q reads (1KB-contiguous wave loads). ---
__launch_bounds__(128)
__global__ void attn9(const unsigned short* __restrict__ qb,
                      const unsigned short* __restrict__ kb,
                      const unsigned short* __restrict__ vT,
                      const int* __restrict__ starts, const int* __restrict__ lengths,
                      unsigned short* __restrict__ ctx, int Npad) {
    __shared__ unsigned short Vt[HD * VP];       // 10.5 KB [dim][key]
    __shared__ unsigned short Pb[2 * 16 * VP];   // 10.5 KB, per-wave halves
    int g = blockIdx.x;
    if (gridDim.x == 1024) {
        int bid = blockIdx.x;
        if (bid < 430) { int r = 96 - bid / 10; g = r + 97 * (bid % 10); }
        else { int b2 = bid - 430; int r = 53 - b2 / 11; g = r + 97 * (b2 % 11); }
    }
    int h = blockIdx.y;
    int start = starts[g], L = lengths[g];
    int t = threadIdx.x;
    int wv = t >> 6, lane = t & 63;
    int l16 = lane & 15, quad = lane >> 4;
    int nk = (L + 15) >> 4;
    int nk2 = (L + 31) >> 5;
    unsigned short* Pw = Pb + wv * 16 * VP;
    // only the odd tail tile is ever read without being written (masked
    // exp stores true zeros for keys in [L, nk*16))
    if (nk & 1) {
        for (int i = lane; i < 128; i += 64) {   // 16 rows x 8 dwords
            int row = i >> 3, c = i & 7;
            ((unsigned*)(Pw + row * VP + nk * 16))[c] = 0u;
        }
    }
    int nch = nk2 * 4;
    for (int i = t; i < HD * nch; i += 128) {
        int r = i / nch, c = i - r * nch;
        *(uint4*)&Vt[r * VP + c * 8] =
            *(const uint4*)(vT + (size_t)(h * HD + r) * Npad + start + c * 8);
    }
    const unsigned short* kh = kb + (size_t)h * Npad * HD;
    const unsigned short* qh = qb + (size_t)h * Npad * HD;
    short8 kf[MAXNK];
    #pragma unroll
    for (int kt = 0; kt < MAXNK; kt++) {
        kf[kt] = (short8){0, 0, 0, 0, 0, 0, 0, 0};
        if (kt < nk) {
            int r = kt * 16 + l16;
            if (r < L) kf[kt] = *(const short8*)(kh + (size_t)(start + r) * HD + quad * 8);
        }
    }
    short8 qf[5];
    #pragma unroll
    for (int i = 0; i < 5; i++) {
        qf[i] = (short8){0, 0, 0, 0, 0, 0, 0, 0};
        int qt = wv + 2 * i;
        if (qt < nk) {
            int qrow = qt * 16 + l16;
            if (qrow < L)
                qf[i] = *(const short8*)(qh + (size_t)(start + qrow) * HD + quad * 8);
        }
    }
    __syncthreads();
    #pragma unroll
    for (int i = 0; i < 5; i++) {
        int qt = wv + 2 * i;
        if (qt >= nk) break;
        int q0 = qt * 16;
        floatx4 sacc[MAXNK];
        #pragma unroll
        for (int kt = 0; kt < MAXNK; kt++)
            if (kt < nk)
                sacc[kt] = __builtin_amdgcn_mfma_f32_16x16x32_bf16(
                    kf[kt], qf[i], (floatx4){0.f, 0.f, 0.f, 0.f}, 0, 0, 0);
        float lsum = 0.f;
        #pragma unroll
        for (int kt = 0; kt < MAXNK; kt++)
            if (kt < nk) {
                #pragma unroll
                for (int r = 0; r < 4; r++) {
                    int key = kt * 16 + quad * 4 + r;
                    // raw 2^x (one v_exp_f32; log2e pre-folded into q)
                    float p = (key < L) ? __builtin_amdgcn_exp2f(sacc[kt][r]) : 0.f;
                    sacc[kt][r] = p;
                    lsum += p;
                }
                *(uint2*)&Pw[l16 * VP + kt * 16 + quad * 4] =
                    make_uint2(pack2i(sacc[kt][0], sacc[kt][1]),
                               pack2i(sacc[kt][2], sacc[kt][3]));
            }
        lsum += __shfl_xor(lsum, 16);
        lsum += __shfl_xor(lsum, 32);
        float inv = 1.f / lsum;
        #pragma unroll
        for (int nc = 0; nc < 2; nc++) {
            // two accumulator chains (kc even/odd): dependent-MFMA chain 5 -> 3
            floatx4 oa = (floatx4){0.f, 0.f, 0.f, 0.f};
            floatx4 ob = (floatx4){0.f, 0.f, 0.f, 0.f};
            #pragma unroll
            for (int kc = 0; kc < 5; kc++)
                if (kc < nk2) {
                    short8 pf = *(const short8*)&Pw[l16 * VP + kc * 32 + quad * 8];
                    short8 vf = *(const short8*)&Vt[(nc * 16 + l16) * VP + kc * 32 + quad * 8];
                    if (kc & 1) ob = __builtin_amdgcn_mfma_f32_16x16x32_bf16(pf, vf, ob, 0, 0, 0);
                    else        oa = __builtin_amdgcn_mfma_f32_16x16x32_bf16(pf, vf, oa, 0, 0, 0);
                }
            #pragma unroll
            for (int r = 0; r < 4; r++) {
                int qr = q0 + quad * 4 + r;
                if (qr < L)
                    ctx[(size_t)(start + qr) * D + h * HD + nc * 16 + l16] =
                        f2bfi((oa[r] + ob[r]) * inv);
            }
        }
    }
}

// ---- tail_fused (512 thr / 8 waves): out2 = LN2(ctx@Wo^T + bo + Q);
// ffn = relu(out2@W1^T+b1)@W2^T + b2; S_u += (out2 + ffn) rows / L.
// out2/fin never leave LDS; pooling flushed via atomicAdd (d_out pre-zeroed).
__launch_bounds__(512)
__global__ void tail_fused(const unsigned short* __restrict__ ctx,
                           const unsigned short* __restrict__ Wo,
                           const float* __restrict__ bo,
                           const unsigned short* __restrict__ Hu,
                           const float* __restrict__ muv, const float* __restrict__ rinvv,
                           const float* __restrict__ g1, const float* __restrict__ b1,
                           const float* __restrict__ g2, const float* __restrict__ b2,
                           const unsigned short* __restrict__ W1,
                           const float* __restrict__ b1f,
                           const unsigned short* __restrict__ W2,
                           const float* __restrict__ b2f,
                           const int* __restrict__ batch_ids,
                           const int* __restrict__ lengths,
                           float* __restrict__ out, int M) {
    __shared__ unsigned short Wl[128 * WP];
    __shared__ int gids[128];
    int t = threadIdx.x;
    int wv = t >> 6, lane = t & 63;       // 8 waves, 16 rows each
    int quad = lane >> 4, l16 = lane & 15;
    int r0 = blockIdx.x * 128;
    int rw = wv * 16;                     // wave's local row base
    int rmax = min(128, M - r0);

    // ---- phase 0: Wo stage + ctx A-fragments + MFMA ------------------------
    for (int i = t; i < 2048; i += 512) {
        int c = i >> 4, kc = (i & 15) * 8;
        *(uint4*)&Wl[c * WP + kc] = *(const uint4*)(Wo + c * 128 + kc);
    }
    if (t < 128) gids[t] = (r0 + t < M) ? batch_ids[r0 + t] : -1;
    short8 af[4];
    {
        int rA = r0 + rw + l16;
        #pragma unroll
        for (int kk = 0; kk < 4; kk++) {
            if (rA < M) af[kk] = *(const short8*)(ctx + (size_t)rA * D + kk * 32 + quad * 8);
            else af[kk] = (short8){0, 0, 0, 0, 0, 0, 0, 0};
        }
    }
    __syncthreads();
    floatx4 acc[8];
    #pragma unroll
    for (int j = 0; j < 8; j++) acc[j] = (floatx4){0.f, 0.f, 0.f, 0.f};
    #pragma unroll
    for (int kk = 0; kk < 4; kk++)
        #pragma unroll
        for (int nt = 0; nt < 8; nt++) {
            short8 bf = *(const short8*)&Wl[(nt * 16 + l16) * WP + kk * 32 + quad * 8];
            acc[nt] = __builtin_amdgcn_mfma_f32_16x16x32_bf16(af[kk], bf, acc[nt], 0, 0, 0);
        }
    __syncthreads();   // done reading Wo

    // ---- phase 1: Hu tile -> LN2 epilogue in-place -> Wl = out2 (bf16) -----
    for (int i = t; i < 2048; i += 512) {
        int row = i >> 4, c8 = (i & 15) * 8;
        uint4 hv = make_uint4(0u, 0u, 0u, 0u);
        if (r0 + row < M) hv = *(const uint4*)(Hu + (size_t)(r0 + row) * D + c8);
        *(uint4*)&Wl[row * WP + c8] = hv;
    }
    __syncthreads();
    {
        float g1c[8], b1c[8], boc[8], g2c[8], b2c[8];
        #pragma unroll
        for (int nt = 0; nt < 8; nt++) {
            int col = nt * 16 + l16;
            g1c[nt] = g1[col]; b1c[nt] = b1[col]; boc[nt] = bo[col];
            g2c[nt] = g2[col]; b2c[nt] = b2[col];
        }
        #pragma unroll
        for (int r = 0; r < 4; r++) {
            int lrow = rw + quad * 4 + r;
            int grow = r0 + lrow;
            bool ok = grow < M;
            float mr = ok ? muv[grow] : 0.f;
            float rr = ok ? rinvv[grow] : 0.f;
            float vv[8];
            float s = 0.f, ss = 0.f;
            #pragma unroll
            for (int nt = 0; nt < 8; nt++) {
                float huv = bf2f(Wl[lrow * WP + nt * 16 + l16]);
                float qv = (huv - mr) * rr * g1c[nt] + b1c[nt];
                float v = acc[nt][r] + boc[nt] + qv;
                vv[nt] = v;
                s += v; ss += v * v;
            }
            #pragma unroll
            for (int o = 1; o < 16; o <<= 1) {
                s += __shfl_xor(s, o, 64);
                ss += __shfl_xor(ss, o, 64);
            }
            float mu = s * (1.f / D);
            float var = ss * (1.f / D) - mu * mu;
            float rinv = rsqrtf(var + 1e-8f);
            #pragma unroll
            for (int nt = 0; nt < 8; nt++)
                Wl[lrow * WP + nt * 16 + l16] =
                    f2bf((vv[nt] - mu) * rinv * g2c[nt] + b2c[nt]);
        }
    }
    // FFN A-fragments read own-wave rows (written by this wave above) --
    // safe BEFORE the barrier; the barrier below is for the cross-wave
    // pooling reads.
    short8 af2[4];
    #pragma unroll
    for (int kk = 0; kk < 4; kk++)
        af2[kk] = *(const short8*)&Wl[(rw + l16) * WP + kk * 32 + quad * 8];
    __syncthreads();

    // ---- phase 2: pooling pass 1 (cross-wave reads of out2) ----------------
    {
        int d = t & 127, qt = t >> 7;      // 4 quarters x 32 rows
        int rlo = qt * 32, rhi = min(rlo + 32, rmax);
        float sum = 0.f;
        int cur = (rlo < rmax) ? gids[rlo] : -1;
        for (int row = rlo; row < rhi; row++) {
            int g = gids[row];
            if (g != cur) {
                atomicAdd(out + (size_t)cur * D + d, sum / (float)lengths[cur]);
                sum = 0.f; cur = g;
            }
            sum += bf2f(Wl[row * WP + d]);
        }
        if (cur >= 0) atomicAdd(out + (size_t)cur * D + d, sum / (float)lengths[cur]);
    }
    __syncthreads();   // out2 fully consumed

    // ---- phase 3: W1 stage, MFMA, relu -> Wl -------------------------------
    for (int i = t; i < 2048; i += 512) {
        int c = i >> 4, kc = (i & 15) * 8;
        *(uint4*)&Wl[c * WP + kc] = *(const uint4*)(W1 + c * 128 + kc);
    }
    __syncthreads();
    #pragma unroll
    for (int j = 0; j < 8; j++) acc[j] = (floatx4){0.f, 0.f, 0.f, 0.f};
    #pragma unroll
    for (int kk = 0; kk < 4; kk++)
        #pragma unroll
        for (int nt = 0; nt < 8; nt++) {
            short8 bf = *(const short8*)&Wl[(nt * 16 + l16) * WP + kk * 32 + quad * 8];
            acc[nt] = __builtin_amdgcn_mfma_f32_16x16x32_bf16(af2[kk], bf, acc[nt], 0, 0, 0);
        }
    __syncthreads();   // done reading W1
    #pragma unroll
    for (int nt = 0; nt < 8; nt++) {
        int col = nt * 16 + l16;
        float bv = b1f[col];
        #pragma unroll
        for (int r = 0; r < 4; r++)
            Wl[(rw + quad * 4 + r) * WP + col] = f2bf(fmaxf(acc[nt][r] + bv, 0.f));
    }
    // af3 reads own-wave rows written just above -- no block barrier needed.
    short8 af3[4];
    #pragma unroll
    for (int kk = 0; kk < 4; kk++)
        af3[kk] = *(const short8*)&Wl[(rw + l16) * WP + kk * 32 + quad * 8];
    __syncthreads();   // all waves done with relu tile before W2 overwrites

    // ---- phase 4: W2 stage, MFMA, ffn2 -> Wl, pooling pass 2 ---------------
    for (int i = t; i < 2048; i += 512) {
        int c = i >> 4, kc = (i & 15) * 8;
        *(uint4*)&Wl[c * WP + kc] = *(const uint4*)(W2 + c * 128 + kc);
    }
    __syncthreads();
    #pragma unroll
    for (int j = 0; j < 8; j++) acc[j] = (floatx4){0.f, 0.f, 0.f, 0.f};
    #pragma unroll
    for (int kk = 0; kk < 4; kk++)
        #pragma unroll
        for (int nt = 0; nt < 8; nt++) {
            short8 bf = *(const short8*)&Wl[(nt * 16 + l16) * WP + kk * 32 + quad * 8];
            acc[nt] = __builtin_amdgcn_mfma_f32_16x16x32_bf16(af3[kk], bf, acc[nt], 0, 0, 0);
        }
    __syncthreads();   // done reading W2
    #pragma unroll
    for (int nt = 0; nt < 8; nt++) {
        int col = nt * 16 + l16;
        float bv = b2f[col];
        #pragma unroll
        for (int r = 0; r < 4; r++)
            Wl[(rw + quad * 4 + r) * WP + col] = f2bf(acc[nt][r] + bv);
    }
    __syncthreads();
    {
        int d = t & 127, qt = t >> 7;      // 4 quarters x 32 rows
        int rlo = qt * 32, rhi = min(rlo + 32, rmax);
        float sum = 0.f;
        int cur = (rlo < rmax) ? gids[rlo] : -1;
        for (int row = rlo; row < rhi; row++) {
            int g = gids[row];
            if (g != cur) {
                atomicAdd(out + (size_t)cur * D + d, sum / (float)lengths[cur]);
                sum = 0.f; cur = g;
            }
            sum += bf2f(Wl[row * WP + d]);
        }
        if (cur >= 0) atomicAdd(out + (size_t)cur * D + d, sum / (float)lengths[cur]);
    }
}

// ---------------------------------------------------------------------------
extern "C" void kernel_launch(void* const* d_in, const int* in_sizes, int n_in,
                              void* d_out, int out_size, void* d_ws, size_t ws_size,
                              hipStream_t stream) {
    const float* POI        = (const float*)d_in[0];
    const float* delta      = (const float*)d_in[1];
    const float* att_W      = (const float*)d_in[2];
    const float* a_src      = (const float*)d_in[3];
    const float* a_dst      = (const float*)d_in[4];
    const float* in_proj_w  = (const float*)d_in[5];
    const float* in_proj_b  = (const float*)d_in[6];
    const float* out_proj_w = (const float*)d_in[7];
    const float* out_proj_b = (const float*)d_in[8];
    const float* ln1_g      = (const float*)d_in[9];
    const float* ln1_b      = (const float*)d_in[10];
    const float* ln2_g      = (const float*)d_in[11];
    const float* ln2_b      = (const float*)d_in[12];
    const float* ffn_w1     = (const float*)d_in[13];
    const float* ffn_b1     = (const float*)d_in[14];
    const float* ffn_w2     = (const float*)d_in[15];
    const float* ffn_b2     = (const float*)d_in[16];
    const int* sess_idx     = (const int*)d_in[17];
    const int* edge_dist    = (const int*)d_in[18];
    const int* batch_ids    = (const int*)d_in[20];
    const int* node_pos     = (const int*)d_in[21];
    const int* lengths      = (const int*)d_in[22];

    int N = in_sizes[17];
    int B = in_sizes[22];
    int gb = (N + 127) / 128;
    int Npad = gb * 128;

    // ---- workspace layout in BYTES, 256-aligned blocks ---------------------
    char* base = (char*)d_ws;
    size_t off = 0;
    auto alloc = [&](size_t bytes) { size_t c = off; off = (off + bytes + 255) & ~(size_t)255; return c; };
    size_t o_csrc  = alloc(D * 4);
    size_t o_cdst  = alloc(D * 4);
    size_t o_t     = alloc(512 * 4);
    size_t o_start = alloc((size_t)B * 4);
    size_t o_mu    = alloc((size_t)N * 4);
    size_t o_ri    = alloc((size_t)N * 4);
    size_t o_u     = alloc(D * 4);
    size_t o_z     = alloc(D * 4);
    size_t o_wb    = alloc(6 * D * D * 2);
    size_t nb      = (size_t)Npad * D * 2;       // one bf16 [Npad,128] buffer
    size_t o_A = alloc(nb);
    size_t o_B = alloc(nb);
    size_t o_C = alloc(nb);
    size_t o_D = alloc(nb);
    if (ws_size < off) return;   // diagnostic: silent fail, no GPU fault

    float* c_src = (float*)(base + o_csrc);
    float* c_dst = (float*)(base + o_cdst);
    float* tb    = (float*)(base + o_t);
    int*   starts = (int*)(base + o_start);
    float* muv   = (float*)(base + o_mu);
    float* rinvv = (float*)(base + o_ri);
    float* u     = (float*)(base + o_u);
    float* z     = (float*)(base + o_z);
    unsigned short* wb = (unsigned short*)(base + o_wb);
    unsigned short* bufA = (unsigned short*)(base + o_A);
    unsigned short* bufB = (unsigned short*)(base + o_B);
    unsigned short* bufC = (unsigned short*)(base + o_C);
    unsigned short* bufD = (unsigned short*)(base + o_D);

    // ---- pipeline ----------------------------------------------------------
    hipMemsetAsync(d_out, 0, (size_t)B * D * 4, stream);   // pooled via atomics
    prep1<<<128, 128, 0, stream>>>(att_W, a_src, a_dst, in_proj_w, in_proj_b,
                                   ln1_g, ln1_b, c_src, c_dst, u, z);
    prep2<<<512, 256, 0, stream>>>(delta, c_src, in_proj_w, out_proj_w,
                                   ffn_w1, ffn_w2, ln1_g, tb, wb);
    gather_hu<<<(N + 7) / 8, 256, 0, stream>>>(POI, sess_idx, node_pos, batch_ids,
                                               edge_dist, lengths, c_src, c_dst, tb,
                                               bufB, muv, rinvv, starts, N);    // Hu=B

    qkv_split<<<dim3(gb, 3), 256, 0, stream>>>(bufB, wb, in_proj_b, u, z, muv, rinvv,
                                               bufC, bufD, bufA, N, Npad);   // q=C, k=D, vT=A

    attn9<<<dim3(B, NHEAD), 128, 0, stream>>>(bufC, bufD, bufA, starts, lengths, bufC, Npad); // ctx=C

    tail_fused<<<gb, 512, 0, stream>>>(bufC, wb + 3 * D * D, out_proj_b, bufB, muv, rinvv,
                                       ln1_g, ln1_b, ln2_g, ln2_b,
                                       wb + 4 * D * D, ffn_b1, wb + 5 * D * D, ffn_b2,
                                       batch_ids, lengths, (float*)d_out, N);
}

// Round 13
// 277.757 us; speedup vs baseline: 1.1992x; 1.0055x over previous
//
#include <hip/hip_runtime.h>
#include <float.h>

// ---------------------------------------------------------------------------
// SeqGraphRepNetwork. Round 35 = round 34 (279.3us, verified best) + s_setprio
// around attn9's MFMA clusters only (T5: +4-7% measured on attention-shaped
// kernels with phase-diverse co-resident waves, m191; NOT applied to
// tail_fused -- barrier-lockstep kernels regress, m190).
// Everything else byte-identical to r34: head-major k/q + coalesced head-slab
// qkv store, attn9 r26 body (Vt+Pb LDS, PV 2-chain), tail_fused 512thr/8wave
// LDS-staged weights, halo gather, parallel prep1.
// ---------------------------------------------------------------------------

#define D 128
#define NHEAD 4
#define HD 32
#define MAXL 160
#define MAXNK 10     // max 16-key tiles (L<=160)
#define VP 168       // Vt / Pb key pitch in ushorts
#define WP 136       // LDS tile pitch in ushorts (272B)

typedef __attribute__((ext_vector_type(8))) short short8;
typedef __attribute__((ext_vector_type(4))) float floatx4;

// ---- bf16 <-> f32 helpers --------------------------------------------------
__device__ __forceinline__ float lo2f(unsigned u) {
    union { unsigned i; float f; } x; x.i = u << 16; return x.f;
}
__device__ __forceinline__ float hi2f(unsigned u) {
    union { unsigned i; float f; } x; x.i = u & 0xffff0000u; return x.f;
}
// single-instruction packed f32->bf16 RNE (gfx950 v_cvt_pk_bf16_f32).
// Used in VALU-throughput-bound kernels only (r23 measured: hurts the
// latency-bound attn9 by constraining the scheduler).
__device__ __forceinline__ unsigned pack2(float a, float b) {
    unsigned r;
    asm("v_cvt_pk_bf16_f32 %0, %1, %2" : "=v"(r) : "v"(a), "v"(b));
    return r;
}
__device__ __forceinline__ unsigned short f2bf(float f) {
    return (unsigned short)pack2(f, 0.f);
}
// integer RNE versions (attn9: latency-bound, these schedule freely)
__device__ __forceinline__ unsigned short f2bfi(float f) {
    union { float f; unsigned i; } x; x.f = f;
    unsigned r = x.i + 0x7fffu + ((x.i >> 16) & 1u);
    return (unsigned short)(r >> 16);
}
__device__ __forceinline__ unsigned pack2i(float a, float b) {
    return (unsigned)f2bfi(a) | ((unsigned)f2bfi(b) << 16);
}
__device__ __forceinline__ float bf2f(unsigned short u) {
    union { unsigned i; float f; } x; x.i = (unsigned)u << 16; return x.f;
}

// ---- prep1: c_src/c_dst = a@att_W; u,z refold vectors ----------------------
// 128 blocks x 128 threads: block p, lanes parallel over q.
__launch_bounds__(128)
__global__ void prep1(const float* __restrict__ att_W, const float* __restrict__ a_src,
                      const float* __restrict__ a_dst, const float* __restrict__ in_proj_w,
                      const float* __restrict__ in_proj_b, const float* __restrict__ g1,
                      const float* __restrict__ b1, float* __restrict__ c_src,
                      float* __restrict__ c_dst, float* __restrict__ u, float* __restrict__ z) {
    int p = blockIdx.x;   // output index
    int q = threadIdx.x;  // reduction index
    __shared__ float red[4][2];
    float w  = att_W[q * D + p];      // column p, parallel across lanes
    float wq = in_proj_w[p * D + q];  // row p, coalesced
    float s  = a_src[q] * w;
    float d  = a_dst[q] * w;
    float su = g1[q] * wq;
    float sz = b1[q] * wq;
    #pragma unroll
    for (int o = 32; o; o >>= 1) {
        s  += __shfl_down(s, o, 64);
        d  += __shfl_down(d, o, 64);
        su += __shfl_down(su, o, 64);
        sz += __shfl_down(sz, o, 64);
    }
    int wv = q >> 6;
    if ((q & 63) == 0) { red[0][wv] = s; red[1][wv] = d; red[2][wv] = su; red[3][wv] = sz; }
    __syncthreads();
    if (q == 0) {
        c_src[p] = red[0][0] + red[0][1];
        c_dst[p] = red[1][0] + red[1][1];
        u[p]     = red[2][0] + red[2][1];
        z[p]     = red[3][0] + red[3][1] + in_proj_b[p];
    }
}

// ---- prep2: blocks 0..127 -> tb (4 buckets each); 128..511 -> bf16 weights -
// wb slots: 0 = W'q (Wq*g1), 1 = Wk, 2 = Wv, 3 = Wo, 4 = W1, 5 = W2.
__global__ void prep2(const float* __restrict__ delta, const float* __restrict__ c_src,
                      const float* __restrict__ in_proj_w, const float* __restrict__ out_proj_w,
                      const float* __restrict__ ffn_w1, const float* __restrict__ ffn_w2,
                      const float* __restrict__ ln1_g, float* __restrict__ tb,
                      unsigned short* __restrict__ wb) {
    int blk = blockIdx.x, t = threadIdx.x;
    if (blk < 128) {
        int b = blk * 4 + (t >> 6);
        int l = t & 63;
        const float* row = delta + (size_t)b * D;
        float s = row[l] * c_src[l] + row[l + 64] * c_src[l + 64];
        #pragma unroll
        for (int o = 32; o; o >>= 1) s += __shfl_down(s, o, 64);
        if (l == 0) tb[b] = s;
    } else {
        int idx = (blk - 128) * 256 + t;   // 384*256 = 98304 = 6*128*128
        int m = idx >> 14;
        int within = idx & (D * D - 1);
        float v;
        if (m == 0) v = in_proj_w[within] * ln1_g[within & (D - 1)];
        else if (m == 1) v = in_proj_w[D * D + within];
        else if (m == 2) v = in_proj_w[2 * D * D + within];
        else if (m == 3) v = out_proj_w[within];
        else if (m == 4) v = ffn_w1[within];
        else v = ffn_w2[within];
        wb[idx] = f2bf(v);
    }
}

// ---- gather_hu: block = 8 nodes + 2-row halo; HALF-WAVE per row. -----------
__launch_bounds__(256)
__global__ void gather_hu(const float* __restrict__ POI, const int* __restrict__ sess_idx,
                          const int* __restrict__ node_pos, const int* __restrict__ batch_ids,
                          const int* __restrict__ edge_dist, const int* __restrict__ lengths,
                          const float* __restrict__ c_src, const float* __restrict__ c_dst,
                          const float* __restrict__ tb, unsigned short* __restrict__ Hu,
                          float* __restrict__ muv, float* __restrict__ rinvv,
                          int* __restrict__ starts, int N) {
    __shared__ unsigned xs[10 * 64];      // 2.5 KB packed bf16x2
    __shared__ float s1s[10], s2s[10];
    int R0 = blockIdx.x * 8;
    int t = threadIdx.x;
    int hw = t >> 5, l32 = t & 31;        // 8 half-waves, 32 lanes each
    float4 cs4 = *(const float4*)(c_src + l32 * 4);
    float4 cd4 = *(const float4*)(c_dst + l32 * 4);
    #pragma unroll
    for (int i = hw; i < 10; i += 8) {
        int n = R0 - 1 + i;
        if (n >= 0 && n < N) {
            int row = sess_idx[n];
            float4 v = *(const float4*)(POI + (size_t)row * D + l32 * 4);
            ((uint2*)(xs + i * 64))[l32] = make_uint2(pack2(v.x, v.y), pack2(v.z, v.w));
            if (i >= 1 && i <= 8) {        // halo dots are never used
                float ps = v.x * cs4.x + v.y * cs4.y + v.z * cs4.z + v.w * cs4.w;
                float pd = v.x * cd4.x + v.y * cd4.y + v.z * cd4.z + v.w * cd4.w;
                #pragma unroll
                for (int o = 16; o; o >>= 1) {   // stays within the 32-half
                    ps += __shfl_down(ps, o, 64);
                    pd += __shfl_down(pd, o, 64);
                }
                if (l32 == 0) { s1s[i] = ps; s2s[i] = pd; }
            }
        }
    }
    __syncthreads();
    int j = hw;                            // one node per half-wave
    int n = R0 + j;
    if (n >= N) return;
    int g = batch_ids[n], pos = node_pos[n], L = lengths[g];
    bool hasF = pos > 0;
    bool hasB = pos < L - 1;
    float la = hasF ? (s1s[j + 1] + tb[edge_dist[n - 1 - g]]) : -FLT_MAX;
    float lb = hasB ? s2s[j + 1] : -FLT_MAX;
    float m = fmaxf(la, lb);
    float ea = hasF ? __expf(la - m) : 0.f;
    float eb = hasB ? __expf(lb - m) : 0.f;
    float inv = 1.f / (ea + eb + 1e-16f);
    float wa = ea * inv, wb = eb * inv;
    uint2 a = hasF ? ((const uint2*)(xs + j * 64))[l32] : make_uint2(0u, 0u);
    uint2 b = hasB ? ((const uint2*)(xs + (j + 2) * 64))[l32] : make_uint2(0u, 0u);
    float h0 = wa * lo2f(a.x) + wb * lo2f(b.x);
    float h1 = wa * hi2f(a.x) + wb * hi2f(b.x);
    float h2 = wa * lo2f(a.y) + wb * lo2f(b.y);
    float h3 = wa * hi2f(a.y) + wb * hi2f(b.y);
    ((uint2*)Hu)[(size_t)n * 32 + l32] = make_uint2(pack2(h0, h1), pack2(h2, h3));
    float s = h0 + h1 + h2 + h3;
    float ss = h0 * h0 + h1 * h1 + h2 * h2 + h3 * h3;
    #pragma unroll
    for (int o = 1; o < 32; o <<= 1) {     // xor <=16 stays within the half
        s += __shfl_xor(s, o, 64);
        ss += __shfl_xor(ss, o, 64);
    }
    if (l32 == 0) {
        float mu = s * (1.f / D);
        float var = ss * (1.f / D) - mu * mu;
        muv[n] = mu;
        rinvv[n] = rsqrtf(var + 1e-8f);
        if (pos == 0) starts[g] = n;
    }
}

// ---- qkv_split: grid (gb, 3); blockIdx.y = pass (0=k, 1=v, 2=q refold). ----
// k and q are written HEAD-MAJOR [4][Npad][32]; v transposed [128][Npad].
__launch_bounds__(256)
__global__ void qkv_split(const unsigned short* __restrict__ Hu, const unsigned short* __restrict__ wb,
                          const float* __restrict__ in_proj_b, const float* __restrict__ u,
                          const float* __restrict__ z, const float* __restrict__ muv,
                          const float* __restrict__ rinvv,
                          unsigned short* __restrict__ qo, unsigned short* __restrict__ ko,
                          unsigned short* __restrict__ vT, int M, int Npad) {
    __shared__ unsigned short Wl[128 * WP];
    int t = threadIdx.x;
    int wv = t >> 6, lane = t & 63;
    int quad = lane >> 4, l16 = lane & 15;
    int r0 = blockIdx.x * 128;
    int rbase = r0 + wv * 32;
    int p = blockIdx.y;
    // 1/sqrt(32) * log2(e): attn uses raw v_exp_f32 (2^x) directly
    const float ASCALE = 0.25504364148122793f;
    const unsigned short* W = wb + (p == 0 ? 1 : p == 1 ? 2 : 0) * (D * D);
    for (int i = t; i < 2048; i += 256) {
        int c = i >> 4, kc = (i & 15) * 8;
        *(uint4*)&Wl[c * WP + kc] = *(const uint4*)(W + c * 128 + kc);
    }
    short8 af[2][4];
    #pragma unroll
    for (int mt = 0; mt < 2; mt++) {
        int r = rbase + mt * 16 + l16;
        #pragma unroll
        for (int kk = 0; kk < 4; kk++) {
            if (r < M) af[mt][kk] = *(const short8*)(Hu + (size_t)r * D + kk * 32 + quad * 8);
            else af[mt][kk] = (short8){0, 0, 0, 0, 0, 0, 0, 0};
        }
    }
    __syncthreads();
    floatx4 acc[2][8];
    #pragma unroll
    for (int i = 0; i < 2; i++)
        #pragma unroll
        for (int j = 0; j < 8; j++) acc[i][j] = (floatx4){0.f, 0.f, 0.f, 0.f};
    #pragma unroll
    for (int kk = 0; kk < 4; kk++)
        #pragma unroll
        for (int nt = 0; nt < 8; nt++) {
            short8 bf = *(const short8*)&Wl[(nt * 16 + l16) * WP + kk * 32 + quad * 8];
            acc[0][nt] = __builtin_amdgcn_mfma_f32_16x16x32_bf16(af[0][kk], bf, acc[0][nt], 0, 0, 0);
            acc[1][nt] = __builtin_amdgcn_mfma_f32_16x16x32_bf16(af[1][kk], bf, acc[1][nt], 0, 0, 0);
        }
    __syncthreads();   // all waves done reading Wl weights
    if (p == 1) {          // vT tile: Wl[col][localnode], paired u32 stores
        #pragma unroll
        for (int nt = 0; nt < 8; nt++) {
            int col = nt * 16 + l16;
            float bv = in_proj_b[2 * D + col];
            #pragma unroll
            for (int mt = 0; mt < 2; mt++)
                #pragma unroll
                for (int r = 0; r < 4; r += 2) {
                    int ln = wv * 32 + mt * 16 + quad * 4 + r;
                    float v0 = (r0 + ln     < M) ? acc[mt][nt][r]     + bv : 0.f;
                    float v1 = (r0 + ln + 1 < M) ? acc[mt][nt][r + 1] + bv : 0.f;
                    *(unsigned*)&Wl[col * WP + ln] = pack2(v0, v1);
                }
        }
        __syncthreads();
        for (int i = t; i < 2048; i += 256) {
            int col = i >> 4, c8 = (i & 15) * 8;
            *(uint4*)(vT + (size_t)col * Npad + r0 + c8) = *(uint4*)&Wl[col * WP + c8];
        }
    } else {
        if (p == 0) {      // k tile: Wl[localrow][col]
            #pragma unroll
            for (int nt = 0; nt < 8; nt++) {
                int col = nt * 16 + l16;
                float bv = in_proj_b[D + col];
                #pragma unroll
                for (int mt = 0; mt < 2; mt++)
                    #pragma unroll
                    for (int r = 0; r < 4; r++)
                        Wl[(wv * 32 + mt * 16 + quad * 4 + r) * WP + col] =
                            f2bf(acc[mt][nt][r] + bv);
            }
        } else {           // q refold tile, pre-scaled by 1/sqrt(32)*log2e
            float uc[8], zc[8];
            #pragma unroll
            for (int nt = 0; nt < 8; nt++) {
                uc[nt] = u[nt * 16 + l16];
                zc[nt] = z[nt * 16 + l16] * ASCALE;
            }
            #pragma unroll
            for (int mt = 0; mt < 2; mt++)
                #pragma unroll
                for (int r = 0; r < 4; r++) {
                    int ln = wv * 32 + mt * 16 + quad * 4 + r;
                    int grow = r0 + ln;
                    float mr = grow < M ? muv[grow] : 0.f;
                    float rr = (grow < M ? rinvv[grow] : 0.f) * ASCALE;
                    #pragma unroll
                    for (int nt = 0; nt < 8; nt++)
                        Wl[ln * WP + nt * 16 + l16] =
                            f2bf(rr * (acc[mt][nt][r] - mr * uc[nt]) + zc[nt]);
                }
        }
        __syncthreads();   // store loop reads cross-wave rows
        unsigned short* outp = (p == 0) ? ko : qo;
        // head-slab-major coalesced store: [head][128 rows][32] -- consecutive
        // threads write consecutive 16B inside one head slab (16KB/iteration).
        for (int i = t; i < 2048; i += 256) {
            int head = i >> 9;             // 0..3
            int j = i & 511;
            int row = j >> 2;              // 0..127
            int c = (j & 3) * 8;           // 0,8,16,24
            if (r0 + row < M)
                *(uint4*)(outp + ((size_t)head * Npad + r0 + row) * HD + c) =
                    *(uint4*)&Wl[row * WP + head * 32 + c];
        }
    }
}

// ---- attn9: r26 body + head-major k/q reads + s_setprio around MFMA
// clusters (T5: waves here are phase-diverse -> scheduler arbitration pays).
__launch_bounds__(128)
__global__ void attn9(const unsigned short* __restrict__ qb,
                      const unsigned short* __restrict__ kb,
                      const unsigned short* __restrict__ vT,
                      const int* __restrict__ starts, const int* __restrict__ lengths,
                      unsigned short* __restrict__ ctx, int Npad) {
    __shared__ unsigned short Vt[HD * VP];       // 10.5 KB [dim][key]
    __shared__ unsigned short Pb[2 * 16 * VP];   // 10.5 KB, per-wave halves
    int g = blockIdx.x;
    if (gridDim.x == 1024) {
        int bid = blockIdx.x;
        if (bid < 430) { int r = 96 - bid / 10; g = r + 97 * (bid % 10); }
        else { int b2 = bid - 430; int r = 53 - b2 / 11; g = r + 97 * (b2 % 11); }
    }
    int h = blockIdx.y;
    int start = starts[g], L = lengths[g];
    int t = threadIdx.x;
    int wv = t >> 6, lane = t & 63;
    int l16 = lane & 15, quad = lane >> 4;
    int nk = (L + 15) >> 4;
    int nk2 = (L + 31) >> 5;
    unsigned short* Pw = Pb + wv * 16 * VP;
    // only the odd tail tile is ever read without being written (masked
    // exp stores true zeros for keys in [L, nk*16))
    if (nk & 1) {
        for (int i = lane; i < 128; i += 64) {   // 16 rows x 8 dwords
            int row = i >> 3, c = i & 7;
            ((unsigned*)(Pw + row * VP + nk * 16))[c] = 0u;
        }
    }
    int nch = nk2 * 4;
    for (int i = t; i < HD * nch; i += 128) {
        int r = i / nch, c = i - r * nch;
        *(uint4*)&Vt[r * VP + c * 8] =
            *(const uint4*)(vT + (size_t)(h * HD + r) * Npad + start + c * 8);
    }
    const unsigned short* kh = kb + (size_t)h * Npad * HD;
    const unsigned short* qh = qb + (size_t)h * Npad * HD;
    short8 kf[MAXNK];
    #pragma unroll
    for (int kt = 0; kt < MAXNK; kt++) {
        kf[kt] = (short8){0, 0, 0, 0, 0, 0, 0, 0};
        if (kt < nk) {
            int r = kt * 16 + l16;
            if (r < L) kf[kt] = *(const short8*)(kh + (size_t)(start + r) * HD + quad * 8);
        }
    }
    short8 qf[5];
    #pragma unroll
    for (int i = 0; i < 5; i++) {
        qf[i] = (short8){0, 0, 0, 0, 0, 0, 0, 0};
        int qt = wv + 2 * i;
        if (qt < nk) {
            int qrow = qt * 16 + l16;
            if (qrow < L)
                qf[i] = *(const short8*)(qh + (size_t)(start + qrow) * HD + quad * 8);
        }
    }
    __syncthreads();
    #pragma unroll
    for (int i = 0; i < 5; i++) {
        int qt = wv + 2 * i;
        if (qt >= nk) break;
        int q0 = qt * 16;
        floatx4 sacc[MAXNK];
        __builtin_amdgcn_s_setprio(1);
        #pragma unroll
        for (int kt = 0; kt < MAXNK; kt++)
            if (kt < nk)
                sacc[kt] = __builtin_amdgcn_mfma_f32_16x16x32_bf16(
                    kf[kt], qf[i], (floatx4){0.f, 0.f, 0.f, 0.f}, 0, 0, 0);
        __builtin_amdgcn_s_setprio(0);
        float lsum = 0.f;
        #pragma unroll
        for (int kt = 0; kt < MAXNK; kt++)
            if (kt < nk) {
                #pragma unroll
                for (int r = 0; r < 4; r++) {
                    int key = kt * 16 + quad * 4 + r;
                    // raw 2^x (one v_exp_f32; log2e pre-folded into q)
                    float p = (key < L) ? __builtin_amdgcn_exp2f(sacc[kt][r]) : 0.f;
                    sacc[kt][r] = p;
                    lsum += p;
                }
                *(uint2*)&Pw[l16 * VP + kt * 16 + quad * 4] =
                    make_uint2(pack2i(sacc[kt][0], sacc[kt][1]),
                               pack2i(sacc[kt][2], sacc[kt][3]));
            }
        lsum += __shfl_xor(lsum, 16);
        lsum += __shfl_xor(lsum, 32);
        float inv = 1.f / lsum;
        #pragma unroll
        for (int nc = 0; nc < 2; nc++) {
            // two accumulator chains (kc even/odd): dependent-MFMA chain 5 -> 3
            floatx4 oa = (floatx4){0.f, 0.f, 0.f, 0.f};
            floatx4 ob = (floatx4){0.f, 0.f, 0.f, 0.f};
            __builtin_amdgcn_s_setprio(1);
            #pragma unroll
            for (int kc = 0; kc < 5; kc++)
                if (kc < nk2) {
                    short8 pf = *(const short8*)&Pw[l16 * VP + kc * 32 + quad * 8];
                    short8 vf = *(const short8*)&Vt[(nc * 16 + l16) * VP + kc * 32 + quad * 8];
                    if (kc & 1) ob = __builtin_amdgcn_mfma_f32_16x16x32_bf16(pf, vf, ob, 0, 0, 0);
                    else        oa = __builtin_amdgcn_mfma_f32_16x16x32_bf16(pf, vf, oa, 0, 0, 0);
                }
            __builtin_amdgcn_s_setprio(0);
            #pragma unroll
            for (int r = 0; r < 4; r++) {
                int qr = q0 + quad * 4 + r;
                if (qr < L)
                    ctx[(size_t)(start + qr) * D + h * HD + nc * 16 + l16] =
                        f2bfi((oa[r] + ob[r]) * inv);
            }
        }
    }
}

// ---- tail_fused (512 thr / 8 waves): out2 = LN2(ctx@Wo^T + bo + Q);
// ffn = relu(out2@W1^T+b1)@W2^T + b2; S_u += (out2 + ffn) rows / L.
// out2/fin never leave LDS; pooling flushed via atomicAdd (d_out pre-zeroed).
__launch_bounds__(512)
__global__ void tail_fused(const unsigned short* __restrict__ ctx,
                           const unsigned short* __restrict__ Wo,
                           const float* __restrict__ bo,
                           const unsigned short* __restrict__ Hu,
                           const float* __restrict__ muv, const float* __restrict__ rinvv,
                           const float* __restrict__ g1, const float* __restrict__ b1,
                           const float* __restrict__ g2, const float* __restrict__ b2,
                           const unsigned short* __restrict__ W1,
                           const float* __restrict__ b1f,
                           const unsigned short* __restrict__ W2,
                           const float* __restrict__ b2f,
                           const int* __restrict__ batch_ids,
                           const int* __restrict__ lengths,
                           float* __restrict__ out, int M) {
    __shared__ unsigned short Wl[128 * WP];
    __shared__ int gids[128];
    int t = threadIdx.x;
    int wv = t >> 6, lane = t & 63;       // 8 waves, 16 rows each
    int quad = lane >> 4, l16 = lane & 15;
    int r0 = blockIdx.x * 128;
    int rw = wv * 16;                     // wave's local row base
    int rmax = min(128, M - r0);

    // ---- phase 0: Wo stage + ctx A-fragments + MFMA ------------------------
    for (int i = t; i < 2048; i += 512) {
        int c = i >> 4, kc = (i & 15) * 8;
        *(uint4*)&Wl[c * WP + kc] = *(const uint4*)(Wo + c * 128 + kc);
    }
    if (t < 128) gids[t] = (r0 + t < M) ? batch_ids[r0 + t] : -1;
    short8 af[4];
    {
        int rA = r0 + rw + l16;
        #pragma unroll
        for (int kk = 0; kk < 4; kk++) {
            if (rA < M) af[kk] = *(const short8*)(ctx + (size_t)rA * D + kk * 32 + quad * 8);
            else af[kk] = (short8){0, 0, 0, 0, 0, 0, 0, 0};
        }
    }
    __syncthreads();
    floatx4 acc[8];
    #pragma unroll
    for (int j = 0; j < 8; j++) acc[j] = (floatx4){0.f, 0.f, 0.f, 0.f};
    #pragma unroll
    for (int kk = 0; kk < 4; kk++)
        #pragma unroll
        for (int nt = 0; nt < 8; nt++) {
            short8 bf = *(const short8*)&Wl[(nt * 16 + l16) * WP + kk * 32 + quad * 8];
            acc[nt] = __builtin_amdgcn_mfma_f32_16x16x32_bf16(af[kk], bf, acc[nt], 0, 0, 0);
        }
    __syncthreads();   // done reading Wo

    // ---- phase 1: Hu tile -> LN2 epilogue in-place -> Wl = out2 (bf16) -----
    for (int i = t; i < 2048; i += 512) {
        int row = i >> 4, c8 = (i & 15) * 8;
        uint4 hv = make_uint4(0u, 0u, 0u, 0u);
        if (r0 + row < M) hv = *(const uint4*)(Hu + (size_t)(r0 + row) * D + c8);
        *(uint4*)&Wl[row * WP + c8] = hv;
    }
    __syncthreads();
    {
        float g1c[8], b1c[8], boc[8], g2c[8], b2c[8];
        #pragma unroll
        for (int nt = 0; nt < 8; nt++) {
            int col = nt * 16 + l16;
            g1c[nt] = g1[col]; b1c[nt] = b1[col]; boc[nt] = bo[col];
            g2c[nt] = g2[col]; b2c[nt] = b2[col];
        }
        #pragma unroll
        for (int r = 0; r < 4; r++) {
            int lrow = rw + quad * 4 + r;
            int grow = r0 + lrow;
            bool ok = grow < M;
            float mr = ok ? muv[grow] : 0.f;
            float rr = ok ? rinvv[grow] : 0.f;
            float vv[8];
            float s = 0.f, ss = 0.f;
            #pragma unroll
            for (int nt = 0; nt < 8; nt++) {
                float huv = bf2f(Wl[lrow * WP + nt * 16 + l16]);
                float qv = (huv - mr) * rr * g1c[nt] + b1c[nt];
                float v = acc[nt][r] + boc[nt] + qv;
                vv[nt] = v;
                s += v; ss += v * v;
            }
            #pragma unroll
            for (int o = 1; o < 16; o <<= 1) {
                s += __shfl_xor(s, o, 64);
                ss += __shfl_xor(ss, o, 64);
            }
            float mu = s * (1.f / D);
            float var = ss * (1.f / D) - mu * mu;
            float rinv = rsqrtf(var + 1e-8f);
            #pragma unroll
            for (int nt = 0; nt < 8; nt++)
                Wl[lrow * WP + nt * 16 + l16] =
                    f2bf((vv[nt] - mu) * rinv * g2c[nt] + b2c[nt]);
        }
    }
    // FFN A-fragments read own-wave rows (written by this wave above) --
    // safe BEFORE the barrier; the barrier below is for the cross-wave
    // pooling reads.
    short8 af2[4];
    #pragma unroll
    for (int kk = 0; kk < 4; kk++)
        af2[kk] = *(const short8*)&Wl[(rw + l16) * WP + kk * 32 + quad * 8];
    __syncthreads();

    // ---- phase 2: pooling pass 1 (cross-wave reads of out2) ----------------
    {
        int d = t & 127, qt = t >> 7;      // 4 quarters x 32 rows
        int rlo = qt * 32, rhi = min(rlo + 32, rmax);
        float sum = 0.f;
        int cur = (rlo < rmax) ? gids[rlo] : -1;
        for (int row = rlo; row < rhi; row++) {
            int g = gids[row];
            if (g != cur) {
                atomicAdd(out + (size_t)cur * D + d, sum / (float)lengths[cur]);
                sum = 0.f; cur = g;
            }
            sum += bf2f(Wl[row * WP + d]);
        }
        if (cur >= 0) atomicAdd(out + (size_t)cur * D + d, sum / (float)lengths[cur]);
    }
    __syncthreads();   // out2 fully consumed

    // ---- phase 3: W1 stage, MFMA, relu -> Wl -------------------------------
    for (int i = t; i < 2048; i += 512) {
        int c = i >> 4, kc = (i & 15) * 8;
        *(uint4*)&Wl[c * WP + kc] = *(const uint4*)(W1 + c * 128 + kc);
    }
    __syncthreads();
    #pragma unroll
    for (int j = 0; j < 8; j++) acc[j] = (floatx4){0.f, 0.f, 0.f, 0.f};
    #pragma unroll
    for (int kk = 0; kk < 4; kk++)
        #pragma unroll
        for (int nt = 0; nt < 8; nt++) {
            short8 bf = *(const short8*)&Wl[(nt * 16 + l16) * WP + kk * 32 + quad * 8];
            acc[nt] = __builtin_amdgcn_mfma_f32_16x16x32_bf16(af2[kk], bf, acc[nt], 0, 0, 0);
        }
    __syncthreads();   // done reading W1
    #pragma unroll
    for (int nt = 0; nt < 8; nt++) {
        int col = nt * 16 + l16;
        float bv = b1f[col];
        #pragma unroll
        for (int r = 0; r < 4; r++)
            Wl[(rw + quad * 4 + r) * WP + col] = f2bf(fmaxf(acc[nt][r] + bv, 0.f));
    }
    // af3 reads own-wave rows written just above -- no block barrier needed.
    short8 af3[4];
    #pragma unroll
    for (int kk = 0; kk < 4; kk++)
        af3[kk] = *(const short8*)&Wl[(rw + l16) * WP + kk * 32 + quad * 8];
    __syncthreads();   // all waves done with relu tile before W2 overwrites

    // ---- phase 4: W2 stage, MFMA, ffn2 -> Wl, pooling pass 2 ---------------
    for (int i = t; i < 2048; i += 512) {
        int c = i >> 4, kc = (i & 15) * 8;
        *(uint4*)&Wl[c * WP + kc] = *(const uint4*)(W2 + c * 128 + kc);
    }
    __syncthreads();
    #pragma unroll
    for (int j = 0; j < 8; j++) acc[j] = (floatx4){0.f, 0.f, 0.f, 0.f};
    #pragma unroll
    for (int kk = 0; kk < 4; kk++)
        #pragma unroll
        for (int nt = 0; nt < 8; nt++) {
            short8 bf = *(const short8*)&Wl[(nt * 16 + l16) * WP + kk * 32 + quad * 8];
            acc[nt] = __builtin_amdgcn_mfma_f32_16x16x32_bf16(af3[kk], bf, acc[nt], 0, 0, 0);
        }
    __syncthreads();   // done reading W2
    #pragma unroll
    for (int nt = 0; nt < 8; nt++) {
        int col = nt * 16 + l16;
        float bv = b2f[col];
        #pragma unroll
        for (int r = 0; r < 4; r++)
            Wl[(rw + quad * 4 + r) * WP + col] = f2bf(acc[nt][r] + bv);
    }
    __syncthreads();
    {
        int d = t & 127, qt = t >> 7;      // 4 quarters x 32 rows
        int rlo = qt * 32, rhi = min(rlo + 32, rmax);
        float sum = 0.f;
        int cur = (rlo < rmax) ? gids[rlo] : -1;
        for (int row = rlo; row < rhi; row++) {
            int g = gids[row];
            if (g != cur) {
                atomicAdd(out + (size_t)cur * D + d, sum / (float)lengths[cur]);
                sum = 0.f; cur = g;
            }
            sum += bf2f(Wl[row * WP + d]);
        }
        if (cur >= 0) atomicAdd(out + (size_t)cur * D + d, sum / (float)lengths[cur]);
    }
}

// ---------------------------------------------------------------------------
extern "C" void kernel_launch(void* const* d_in, const int* in_sizes, int n_in,
                              void* d_out, int out_size, void* d_ws, size_t ws_size,
                              hipStream_t stream) {
    const float* POI        = (const float*)d_in[0];
    const float* delta      = (const float*)d_in[1];
    const float* att_W      = (const float*)d_in[2];
    const float* a_src      = (const float*)d_in[3];
    const float* a_dst      = (const float*)d_in[4];
    const float* in_proj_w  = (const float*)d_in[5];
    const float* in_proj_b  = (const float*)d_in[6];
    const float* out_proj_w = (const float*)d_in[7];
    const float* out_proj_b = (const float*)d_in[8];
    const float* ln1_g      = (const float*)d_in[9];
    const float* ln1_b      = (const float*)d_in[10];
    const float* ln2_g      = (const float*)d_in[11];
    const float* ln2_b      = (const float*)d_in[12];
    const float* ffn_w1     = (const float*)d_in[13];
    const float* ffn_b1     = (const float*)d_in[14];
    const float* ffn_w2     = (const float*)d_in[15];
    const float* ffn_b2     = (const float*)d_in[16];
    const int* sess_idx     = (const int*)d_in[17];
    const int* edge_dist    = (const int*)d_in[18];
    const int* batch_ids    = (const int*)d_in[20];
    const int* node_pos     = (const int*)d_in[21];
    const int* lengths      = (const int*)d_in[22];

    int N = in_sizes[17];
    int B = in_sizes[22];
    int gb = (N + 127) / 128;
    int Npad = gb * 128;

    // ---- workspace layout in BYTES, 256-aligned blocks ---------------------
    char* base = (char*)d_ws;
    size_t off = 0;
    auto alloc = [&](size_t bytes) { size_t c = off; off = (off + bytes + 255) & ~(size_t)255; return c; };
    size_t o_csrc  = alloc(D * 4);
    size_t o_cdst  = alloc(D * 4);
    size_t o_t     = alloc(512 * 4);
    size_t o_start = alloc((size_t)B * 4);
    size_t o_mu    = alloc((size_t)N * 4);
    size_t o_ri    = alloc((size_t)N * 4);
    size_t o_u     = alloc(D * 4);
    size_t o_z     = alloc(D * 4);
    size_t o_wb    = alloc(6 * D * D * 2);
    size_t nb      = (size_t)Npad * D * 2;       // one bf16 [Npad,128] buffer
    size_t o_A = alloc(nb);
    size_t o_B = alloc(nb);
    size_t o_C = alloc(nb);
    size_t o_D = alloc(nb);
    if (ws_size < off) return;   // diagnostic: silent fail, no GPU fault

    float* c_src = (float*)(base + o_csrc);
    float* c_dst = (float*)(base + o_cdst);
    float* tb    = (float*)(base + o_t);
    int*   starts = (int*)(base + o_start);
    float* muv   = (float*)(base + o_mu);
    float* rinvv = (float*)(base + o_ri);
    float* u     = (float*)(base + o_u);
    float* z     = (float*)(base + o_z);
    unsigned short* wb = (unsigned short*)(base + o_wb);
    unsigned short* bufA = (unsigned short*)(base + o_A);
    unsigned short* bufB = (unsigned short*)(base + o_B);
    unsigned short* bufC = (unsigned short*)(base + o_C);
    unsigned short* bufD = (unsigned short*)(base + o_D);

    // ---- pipeline ----------------------------------------------------------
    hipMemsetAsync(d_out, 0, (size_t)B * D * 4, stream);   // pooled via atomics
    prep1<<<128, 128, 0, stream>>>(att_W, a_src, a_dst, in_proj_w, in_proj_b,
                                   ln1_g, ln1_b, c_src, c_dst, u, z);
    prep2<<<512, 256, 0, stream>>>(delta, c_src, in_proj_w, out_proj_w,
                                   ffn_w1, ffn_w2, ln1_g, tb, wb);
    gather_hu<<<(N + 7) / 8, 256, 0, stream>>>(POI, sess_idx, node_pos, batch_ids,
                                               edge_dist, lengths, c_src, c_dst, tb,
                                               bufB, muv, rinvv, starts, N);    // Hu=B

    qkv_split<<<dim3(gb, 3), 256, 0, stream>>>(bufB, wb, in_proj_b, u, z, muv, rinvv,
                                               bufC, bufD, bufA, N, Npad);   // q=C, k=D, vT=A

    attn9<<<dim3(B, NHEAD), 128, 0, stream>>>(bufC, bufD, bufA, starts, lengths, bufC, Npad); // ctx=C

    tail_fused<<<gb, 512, 0, stream>>>(bufC, wb + 3 * D * D, out_proj_b, bufB, muv, rinvv,
                                       ln1_g, ln1_b, ln2_g, ln2_b,
                                       wb + 4 * D * D, ffn_b1, wb + 5 * D * D, ffn_b2,
                                       batch_ids, lengths, (float*)d_out, N);
}